// Round 9
// baseline (102.052 us; speedup 1.0000x reference)
//
#include <hip/hip_runtime.h>
#include <hip/hip_bf16.h>
#include <hip/hip_fp16.h>
#include <math.h>

#define N_NODES 20000
#define N_EDGES 320000
#define E_TOT   (N_EDGES + N_NODES)
#define N_FEAT  128
#define NEG_SLOPE 0.2f
#define MAXDEG  96   // padded adjacency stride; in-degree ~Binom mean 17, max ~45 << 96

typedef _Float16 half8 __attribute__((ext_vector_type(8)));
typedef float f32x4 __attribute__((ext_vector_type(4)));

// ---- zero per-node edge cursor (ws poisoned 0xAA -> must init every call) ----
__global__ void k_zero(int* __restrict__ cur){
  int i = blockIdx.x * blockDim.x + threadIdx.x;
  if (i < N_NODES) cur[i] = 0;
}

// ---- fused: padded-adjacency build + x->fp16 convert + W1 fp16-transpose ----
__global__ void k_pre(const int* __restrict__ ei, int* __restrict__ cur,
                      int* __restrict__ adjS,
                      const float* __restrict__ x, _Float16* __restrict__ xh,
                      const float* __restrict__ W1, _Float16* __restrict__ W1t){
  int tid = blockIdx.x * blockDim.x + threadIdx.x;
  if (tid < E_TOT){
    int s, d;
    if (tid < N_EDGES){ s = ei[tid]; d = ei[N_EDGES + tid]; }
    else              { s = d = tid - N_EDGES; }
    int pos = atomicAdd(&cur[d], 1);
    if (pos < MAXDEG) adjS[d * MAXDEG + pos] = s;
  }
  if (tid < (N_NODES * N_FEAT / 8)){           // 320000 chunks of 8
    float4 a = *(const float4*)&x[(size_t)tid * 8];
    float4 b = *(const float4*)&x[(size_t)tid * 8 + 4];
    union { __half2 h2[4]; half8 h8; } u;
    u.h2[0] = __floats2half2_rn(a.x, a.y);
    u.h2[1] = __floats2half2_rn(a.z, a.w);
    u.h2[2] = __floats2half2_rn(b.x, b.y);
    u.h2[3] = __floats2half2_rn(b.z, b.w);
    *(half8*)&xh[(size_t)tid * 8] = u.h8;
  }
  int u2 = tid - (N_NODES * N_FEAT / 8);
  if (u2 >= 0 && u2 < 4096){                   // W1t[256 n][128 k]
    int n = u2 >> 4, ks = u2 & 15;
    union { __half2 h2[4]; half8 h8; } u;
    float v[8];
    #pragma unroll
    for (int r = 0; r < 8; ++r) v[r] = W1[(size_t)(ks * 8 + r) * 256 + n];
    u.h2[0] = __floats2half2_rn(v[0], v[1]);
    u.h2[1] = __floats2half2_rn(v[2], v[3]);
    u.h2[2] = __floats2half2_rn(v[4], v[5]);
    u.h2[3] = __floats2half2_rn(v[6], v[7]);
    *(half8*)&W1t[(size_t)n * 128 + ks * 8] = u.h8;
  }
}

// ---- GEMM1 via MFMA fp16: h1h = x @ W1 [20000,256] + fused logit projections ----
__global__ __launch_bounds__(256) void k_gemm1(
                        const _Float16* __restrict__ xh, const _Float16* __restrict__ W1t,
                        const float* __restrict__ as1, const float* __restrict__ ad1,
                        _Float16* __restrict__ h1h,
                        float* __restrict__ alS, float* __restrict__ alD){
  __shared__ _Float16 xt[64][136];   // [m][k], pad 8 halves
  __shared__ _Float16 Wt[64][136];   // [n][k]
  int t  = threadIdx.x;
  int m0 = blockIdx.x * 64;
  int by = blockIdx.y;               // head
  int j0 = by * 64;
  #pragma unroll
  for (int ii = 0; ii < 4; ++ii){
    int f = t + ii * 256;            // 1024 slots = 64 rows x 16 half8
    int r = f >> 4, s = f & 15;
    half8 xv = (half8)(_Float16)0.f;
    if (m0 + r < N_NODES) xv = *(const half8*)&xh[(size_t)(m0 + r) * 128 + s * 8];
    *(half8*)&xt[r][s * 8] = xv;
    half8 wv = *(const half8*)&W1t[(size_t)(j0 + r) * 128 + s * 8];
    *(half8*)&Wt[r][s * 8] = wv;
  }
  __syncthreads();

  int w = t >> 6, lane = t & 63;
  int g = lane >> 4, mi = lane & 15;
  f32x4 acc[4] = {};
  #pragma unroll
  for (int kk = 0; kk < 4; ++kk){
    int ko = kk * 32 + g * 8;
    half8 b = *(const half8*)&xt[w * 16 + mi][ko];
    #pragma unroll
    for (int s = 0; s < 4; ++s){
      half8 a = *(const half8*)&Wt[s * 16 + mi][ko];
      acc[s] = __builtin_amdgcn_mfma_f32_16x16x32_f16(a, b, acc[s], 0, 0, 0);
    }
  }

  int m = m0 + w * 16 + mi;
  float s_ = 0.f, d_ = 0.f;
  #pragma unroll
  for (int s = 0; s < 4; ++s){
    int nb = j0 + s * 16 + g * 4;
    float4 asv = *(const float4*)&as1[nb];
    float4 adv = *(const float4*)&ad1[nb];
    s_ += acc[s][0] * asv.x + acc[s][1] * asv.y + acc[s][2] * asv.z + acc[s][3] * asv.w;
    d_ += acc[s][0] * adv.x + acc[s][1] * adv.y + acc[s][2] * adv.z + acc[s][3] * adv.w;
    if (m < N_NODES){
      union { __half2 h2[2]; float2 f2; } u;
      u.h2[0] = __floats2half2_rn(acc[s][0], acc[s][1]);
      u.h2[1] = __floats2half2_rn(acc[s][2], acc[s][3]);
      *(float2*)&h1h[(size_t)m * 256 + nb] = u.f2;
    }
  }
  s_ += __shfl_xor(s_, 16); s_ += __shfl_xor(s_, 32);
  d_ += __shfl_xor(d_, 16); d_ += __shfl_xor(d_, 32);
  if (g == 0 && m < N_NODES){ alS[m * 4 + by] = s_; alD[m * 4 + by] = d_; }
}

// ---- layer-1 single-pass softmax+aggregate+bias+ELU (fp16 gathers, 8-way ILP).
// Writes helu as fp16 (read densely by MFMA gemm2). head = blockIdx&3 keeps each
// XCD's gather footprint to one 2.56MB head slice.
__global__ __launch_bounds__(256) void k_attn1(
                        const int* __restrict__ cur, const int* __restrict__ adjS,
                        const __half* __restrict__ h1h,
                        const float* __restrict__ alS, const float* __restrict__ alD,
                        const float* __restrict__ b1, _Float16* __restrict__ heluh){
  int b    = blockIdx.x;
  int slot = b & 7;
  int h    = slot & 3;
  int g    = (slot >> 2) * 625 + (b >> 3);    // node group [0,1250)
  int t    = threadIdx.x;
  int w    = t >> 6, lane = t & 63;
  int grp  = lane >> 4, l16 = lane & 15;
  int n    = g * 16 + w * 4 + grp;

  int cnt  = cur[n]; cnt = (cnt > MAXDEG) ? MAXDEG : cnt;
  int start = n * MAXDEG, end = start + cnt;
  float ald = alD[n * 4 + h];
  const __half* __restrict__ hb = h1h + h * 64 + l16 * 4;

  float4 A[8]; float dn[8];
  #pragma unroll
  for (int q = 0; q < 8; ++q){ A[q] = make_float4(0.f,0.f,0.f,0.f); dn[q] = 0.f; }

  int i = start;
  for (; i + 7 < end; i += 8){
    int ss[8]; float ww[8];
    #pragma unroll
    for (int q = 0; q < 8; ++q) ss[q] = adjS[i + q];
    #pragma unroll
    for (int q = 0; q < 8; ++q){
      float tt = alS[ss[q] * 4 + h] + ald;
      tt = (tt > 0.f) ? tt : NEG_SLOPE * tt;
      ww[q] = __expf(tt);
    }
    #pragma unroll
    for (int q = 0; q < 8; ++q){
      float2 rr = *(const float2*)&hb[(size_t)ss[q] * 256];
      const __half2* pp = (const __half2*)&rr;
      float2 va = __half22float2(pp[0]), vb = __half22float2(pp[1]);
      A[q].x += ww[q] * va.x; A[q].y += ww[q] * va.y;
      A[q].z += ww[q] * vb.x; A[q].w += ww[q] * vb.y;
      dn[q] += ww[q];
    }
  }
  for (; i < end; ++i){
    int s0 = adjS[i];
    float tt = alS[s0 * 4 + h] + ald;
    tt = (tt > 0.f) ? tt : NEG_SLOPE * tt;
    float w0 = __expf(tt);
    float2 rr = *(const float2*)&hb[(size_t)s0 * 256];
    const __half2* pp = (const __half2*)&rr;
    float2 va = __half22float2(pp[0]), vb = __half22float2(pp[1]);
    A[0].x += w0 * va.x; A[0].y += w0 * va.y; A[0].z += w0 * vb.x; A[0].w += w0 * vb.y;
    dn[0] += w0;
  }
  #pragma unroll
  for (int q = 4; q > 0; q >>= 1)
    #pragma unroll
    for (int p = 0; p < q; ++p){
      A[p].x += A[p + q].x; A[p].y += A[p + q].y;
      A[p].z += A[p + q].z; A[p].w += A[p + q].w;
      dn[p] += dn[p + q];
    }
  float rinv = 1.f / (dn[0] + 1e-16f);
  float4 bv = *(const float4*)&b1[h * 64 + l16 * 4];
  float4 o;
  o.x = A[0].x * rinv + bv.x;
  o.y = A[0].y * rinv + bv.y;
  o.z = A[0].z * rinv + bv.z;
  o.w = A[0].w * rinv + bv.w;
  o.x = (o.x > 0.f) ? o.x : (__expf(o.x) - 1.f);
  o.y = (o.y > 0.f) ? o.y : (__expf(o.y) - 1.f);
  o.z = (o.z > 0.f) ? o.z : (__expf(o.z) - 1.f);
  o.w = (o.w > 0.f) ? o.w : (__expf(o.w) - 1.f);
  union { __half2 h2[2]; float2 f2; } u;
  u.h2[0] = __floats2half2_rn(o.x, o.y);
  u.h2[1] = __floats2half2_rn(o.z, o.w);
  *(float2*)&heluh[(size_t)n * 256 + h * 64 + l16 * 4] = u.f2;
}

// ---- GEMM2 via MFMA fp16: h2 = helu @ W2 [20000,16] (pre-bias) + fused projections.
// Same verified operand convention as gemm1: a = W2t col-panel (lane&15), b = node
// panel (lane&15), g = lane>>4 picks k-subchunk; lane's f32x4 = 4 consecutive cols.
__global__ __launch_bounds__(256) void k_gemm2(
                        const _Float16* __restrict__ heluh, const float* __restrict__ W2,
                        const float* __restrict__ as2, const float* __restrict__ ad2,
                        float* __restrict__ h2, float* __restrict__ alS, float* __restrict__ alD){
  __shared__ _Float16 Ht[64][264];   // [node][k], pad 8
  __shared__ _Float16 Wt[16][264];   // [col][k]
  int t = threadIdx.x;
  int n0 = blockIdx.x * 64;
  #pragma unroll
  for (int ii = 0; ii < 8; ++ii){
    int f = t + ii * 256;            // 2048 slots = 64 rows x 32 half8
    int r = f >> 5, s = f & 31;
    half8 v = (half8)(_Float16)0.f;
    if (n0 + r < N_NODES) v = *(const half8*)&heluh[(size_t)(n0 + r) * 256 + s * 8];
    *(half8*)&Ht[r][s * 8] = v;
  }
  {                                   // W2 [256 k][16 col] fp32 -> Wt[16][256] fp16
    int k = t;
    float4 w0 = *(const float4*)&W2[k * 16 + 0];
    float4 w1 = *(const float4*)&W2[k * 16 + 4];
    float4 w2 = *(const float4*)&W2[k * 16 + 8];
    float4 w3 = *(const float4*)&W2[k * 16 + 12];
    float wv[16] = {w0.x,w0.y,w0.z,w0.w, w1.x,w1.y,w1.z,w1.w,
                    w2.x,w2.y,w2.z,w2.w, w3.x,w3.y,w3.z,w3.w};
    #pragma unroll
    for (int c = 0; c < 16; ++c) Wt[c][k] = (_Float16)wv[c];
  }
  __syncthreads();

  int w = t >> 6, lane = t & 63;
  int g = lane >> 4, mi = lane & 15;
  f32x4 acc = {};
  #pragma unroll
  for (int kk = 0; kk < 8; ++kk){
    int ko = kk * 32 + g * 8;
    half8 b = *(const half8*)&Ht[w * 16 + mi][ko];
    half8 a = *(const half8*)&Wt[mi][ko];
    acc = __builtin_amdgcn_mfma_f32_16x16x32_f16(a, b, acc, 0, 0, 0);
  }
  int n = n0 + w * 16 + mi;
  float4 asv = *(const float4*)&as2[g * 4];
  float4 adv = *(const float4*)&ad2[g * 4];
  float s_ = acc[0] * asv.x + acc[1] * asv.y + acc[2] * asv.z + acc[3] * asv.w;
  float d_ = acc[0] * adv.x + acc[1] * adv.y + acc[2] * adv.z + acc[3] * adv.w;
  s_ += __shfl_xor(s_, 16); s_ += __shfl_xor(s_, 32);
  d_ += __shfl_xor(d_, 16); d_ += __shfl_xor(d_, 32);
  if (n < N_NODES){
    float4 hv = make_float4(acc[0], acc[1], acc[2], acc[3]);
    *(float4*)&h2[(size_t)n * 16 + g * 4] = hv;   // pre-bias
    if (g == 0){ alS[n] = s_; alD[n] = d_; }
  }
}

// ---- layer-2 single-pass softmax+aggregate+bias -> d_out. ----
__global__ __launch_bounds__(256) void k_attn2(
                        const int* __restrict__ cur, const int* __restrict__ adjS,
                        const float* __restrict__ h2,
                        const float* __restrict__ alS, const float* __restrict__ alD,
                        const float* __restrict__ b2, float* __restrict__ out){
  int t    = threadIdx.x;
  int w    = t >> 6, lane = t & 63;
  int grp  = lane >> 4, l16 = lane & 15;
  int j    = l16 >> 2, c4 = l16 & 3;
  int n    = blockIdx.x * 16 + w * 4 + grp;

  int cnt  = cur[n]; cnt = (cnt > MAXDEG) ? MAXDEG : cnt;
  int start = n * MAXDEG, end = start + cnt;
  float ald = alD[n];
  float4 acc = make_float4(0.f,0.f,0.f,0.f);
  float den = 0.f;
  for (int i = start + j; i < end; i += 4){
    int s = adjS[i];
    float tt = alS[s] + ald;
    tt = (tt > 0.f) ? tt : NEG_SLOPE * tt;
    float wv = __expf(tt);
    float4 v = *(const float4*)&h2[(size_t)s * 16 + c4 * 4];
    acc.x += wv * v.x; acc.y += wv * v.y; acc.z += wv * v.z; acc.w += wv * v.w;
    den += wv;
  }
  #pragma unroll
  for (int off = 4; off <= 8; off <<= 1){
    acc.x += __shfl_xor(acc.x, off);
    acc.y += __shfl_xor(acc.y, off);
    acc.z += __shfl_xor(acc.z, off);
    acc.w += __shfl_xor(acc.w, off);
    den   += __shfl_xor(den, off);
  }
  if (j == 0){
    float rinv = 1.f / (den + 1e-16f);
    float4 bv = *(const float4*)&b2[c4 * 4];
    float4 o;
    o.x = acc.x * rinv + bv.x; o.y = acc.y * rinv + bv.y;
    o.z = acc.z * rinv + bv.z; o.w = acc.w * rinv + bv.w;
    *(float4*)&out[(size_t)n * 16 + c4 * 4] = o;
  }
}

extern "C" void kernel_launch(void* const* d_in, const int* in_sizes, int n_in,
                              void* d_out, int out_size, void* d_ws, size_t ws_size,
                              hipStream_t stream){
  const float* x   = (const float*)d_in[0];
  const int*   ei  = (const int*)d_in[1];
  const float* W1  = (const float*)d_in[2];
  const float* as1 = (const float*)d_in[3];
  const float* ad1 = (const float*)d_in[4];
  const float* b1  = (const float*)d_in[5];
  const float* W2  = (const float*)d_in[6];
  const float* as2 = (const float*)d_in[7];
  const float* ad2 = (const float*)d_in[8];
  const float* b2  = (const float*)d_in[9];
  float* out = (float*)d_out;

  float* fws = (float*)d_ws;
  size_t off = 0;
  __half* h1h = (__half*)(fws + off); off += (size_t)N_NODES * 128;      // fp16 [20000,256]
  _Float16* xh  = (_Float16*)(fws + off); off += (size_t)N_NODES * 64;    // fp16 [20000,128]
  _Float16* W1t = (_Float16*)(fws + off); off += 256 * 64;                // fp16 [256,128]
  _Float16* heluh = (_Float16*)(fws + off); off += (size_t)N_NODES * 128; // fp16 [20000,256]
  float* h2   = fws + off; off += (size_t)N_NODES * 16;
  float* alS1 = fws + off; off += N_NODES * 4;
  float* alD1 = fws + off; off += N_NODES * 4;
  float* alS2 = fws + off; off += N_NODES;
  float* alD2 = fws + off; off += N_NODES;
  int* cur  = (int*)(fws + off); off += N_NODES;
  int* adjS = (int*)(fws + off); off += (size_t)N_NODES * MAXDEG;

  const int XW = N_NODES * N_FEAT / 8 + 4096;      // x-convert + W1t jobs
  const int PRE_N = (E_TOT > XW ? E_TOT : XW);

  k_zero<<<(N_NODES + 255) / 256, 256, 0, stream>>>(cur);
  k_pre<<<(PRE_N + 255) / 256, 256, 0, stream>>>(ei, cur, adjS, x, xh, W1, W1t);
  k_gemm1<<<dim3(313, 4), 256, 0, stream>>>(xh, W1t, as1, ad1, (_Float16*)h1h, alS1, alD1);
  k_attn1<<<5000, 256, 0, stream>>>(cur, adjS, h1h, alS1, alD1, b1, heluh);
  k_gemm2<<<313, 256, 0, stream>>>(heluh, W2, as2, ad2, h2, alS2, alD2);
  k_attn2<<<1250, 256, 0, stream>>>(cur, adjS, h2, alS2, alD2, b2, out);
}

// Round 10
// 91.115 us; speedup vs baseline: 1.1200x; 1.1200x over previous
//
#include <hip/hip_runtime.h>
#include <hip/hip_bf16.h>
#include <hip/hip_fp16.h>
#include <math.h>

#define N_NODES 20000
#define N_EDGES 320000
#define E_TOT   (N_EDGES + N_NODES)
#define N_FEAT  128
#define NEG_SLOPE 0.2f
#define MAXDEG  96   // padded adjacency stride; in-degree ~Binom mean 17, max ~45 << 96

typedef _Float16 half8 __attribute__((ext_vector_type(8)));
typedef float f32x4 __attribute__((ext_vector_type(4)));

// ---- zero per-node edge cursor (ws poisoned 0xAA -> must init every call) ----
__global__ void k_zero(int* __restrict__ cur){
  int i = blockIdx.x * blockDim.x + threadIdx.x;
  if (i < N_NODES) cur[i] = 0;
}

// ---- fused: padded-adjacency build + x->fp16 convert + W1 fp16-transpose ----
__global__ void k_pre(const int* __restrict__ ei, int* __restrict__ cur,
                      int* __restrict__ adjS,
                      const float* __restrict__ x, _Float16* __restrict__ xh,
                      const float* __restrict__ W1, _Float16* __restrict__ W1t){
  int tid = blockIdx.x * blockDim.x + threadIdx.x;
  if (tid < E_TOT){
    int s, d;
    if (tid < N_EDGES){ s = ei[tid]; d = ei[N_EDGES + tid]; }
    else              { s = d = tid - N_EDGES; }
    int pos = atomicAdd(&cur[d], 1);
    if (pos < MAXDEG) adjS[d * MAXDEG + pos] = s;
  }
  if (tid < (N_NODES * N_FEAT / 8)){           // 320000 chunks of 8
    float4 a = *(const float4*)&x[(size_t)tid * 8];
    float4 b = *(const float4*)&x[(size_t)tid * 8 + 4];
    union { __half2 h2[4]; half8 h8; } u;
    u.h2[0] = __floats2half2_rn(a.x, a.y);
    u.h2[1] = __floats2half2_rn(a.z, a.w);
    u.h2[2] = __floats2half2_rn(b.x, b.y);
    u.h2[3] = __floats2half2_rn(b.z, b.w);
    *(half8*)&xh[(size_t)tid * 8] = u.h8;
  }
  int u2 = tid - (N_NODES * N_FEAT / 8);
  if (u2 >= 0 && u2 < 4096){                   // W1t[256 n][128 k]
    int n = u2 >> 4, ks = u2 & 15;
    union { __half2 h2[4]; half8 h8; } u;
    float v[8];
    #pragma unroll
    for (int r = 0; r < 8; ++r) v[r] = W1[(size_t)(ks * 8 + r) * 256 + n];
    u.h2[0] = __floats2half2_rn(v[0], v[1]);
    u.h2[1] = __floats2half2_rn(v[2], v[3]);
    u.h2[2] = __floats2half2_rn(v[4], v[5]);
    u.h2[3] = __floats2half2_rn(v[6], v[7]);
    *(half8*)&W1t[(size_t)n * 128 + ks * 8] = u.h8;
  }
}

// ---- GEMM1 via MFMA fp16: h1h = x @ W1 [20000,256] + fused logit projections ----
__global__ __launch_bounds__(256) void k_gemm1(
                        const _Float16* __restrict__ xh, const _Float16* __restrict__ W1t,
                        const float* __restrict__ as1, const float* __restrict__ ad1,
                        _Float16* __restrict__ h1h,
                        float* __restrict__ alS, float* __restrict__ alD){
  __shared__ _Float16 xt[64][136];   // [m][k], pad 8 halves
  __shared__ _Float16 Wt[64][136];   // [n][k]
  int t  = threadIdx.x;
  int m0 = blockIdx.x * 64;
  int by = blockIdx.y;               // head
  int j0 = by * 64;
  #pragma unroll
  for (int ii = 0; ii < 4; ++ii){
    int f = t + ii * 256;            // 1024 slots = 64 rows x 16 half8
    int r = f >> 4, s = f & 15;
    half8 xv = (half8)(_Float16)0.f;
    if (m0 + r < N_NODES) xv = *(const half8*)&xh[(size_t)(m0 + r) * 128 + s * 8];
    *(half8*)&xt[r][s * 8] = xv;
    half8 wv = *(const half8*)&W1t[(size_t)(j0 + r) * 128 + s * 8];
    *(half8*)&Wt[r][s * 8] = wv;
  }
  __syncthreads();

  int w = t >> 6, lane = t & 63;
  int g = lane >> 4, mi = lane & 15;
  f32x4 acc[4] = {};
  #pragma unroll
  for (int kk = 0; kk < 4; ++kk){
    int ko = kk * 32 + g * 8;
    half8 b = *(const half8*)&xt[w * 16 + mi][ko];
    #pragma unroll
    for (int s = 0; s < 4; ++s){
      half8 a = *(const half8*)&Wt[s * 16 + mi][ko];
      acc[s] = __builtin_amdgcn_mfma_f32_16x16x32_f16(a, b, acc[s], 0, 0, 0);
    }
  }

  int m = m0 + w * 16 + mi;
  float s_ = 0.f, d_ = 0.f;
  #pragma unroll
  for (int s = 0; s < 4; ++s){
    int nb = j0 + s * 16 + g * 4;
    float4 asv = *(const float4*)&as1[nb];
    float4 adv = *(const float4*)&ad1[nb];
    s_ += acc[s][0] * asv.x + acc[s][1] * asv.y + acc[s][2] * asv.z + acc[s][3] * asv.w;
    d_ += acc[s][0] * adv.x + acc[s][1] * adv.y + acc[s][2] * adv.z + acc[s][3] * adv.w;
    if (m < N_NODES){
      union { __half2 h2[2]; float2 f2; } u;
      u.h2[0] = __floats2half2_rn(acc[s][0], acc[s][1]);
      u.h2[1] = __floats2half2_rn(acc[s][2], acc[s][3]);
      *(float2*)&h1h[(size_t)m * 256 + nb] = u.f2;
    }
  }
  s_ += __shfl_xor(s_, 16); s_ += __shfl_xor(s_, 32);
  d_ += __shfl_xor(d_, 16); d_ += __shfl_xor(d_, 32);
  if (g == 0 && m < N_NODES){ alS[m * 4 + by] = s_; alD[m * 4 + by] = d_; }
}

// ---- layer-1 single-pass softmax+aggregate+bias+ELU (fp16 gathers, 4-way ILP).
// R8-proven codegen shape; only change: helu stored fp16 for MFMA gemm2.
// head = blockIdx&3 keeps each XCD's gather footprint to one 2.56MB head slice.
__global__ __launch_bounds__(256) void k_attn1(
                        const int* __restrict__ cur, const int* __restrict__ adjS,
                        const __half* __restrict__ h1h,
                        const float* __restrict__ alS, const float* __restrict__ alD,
                        const float* __restrict__ b1, _Float16* __restrict__ heluh){
  int b    = blockIdx.x;
  int slot = b & 7;
  int h    = slot & 3;
  int g    = (slot >> 2) * 625 + (b >> 3);    // node group [0,1250)
  int t    = threadIdx.x;
  int w    = t >> 6, lane = t & 63;
  int grp  = lane >> 4, l16 = lane & 15;
  int n    = g * 16 + w * 4 + grp;

  int cnt  = cur[n]; cnt = (cnt > MAXDEG) ? MAXDEG : cnt;
  int start = n * MAXDEG, end = start + cnt;
  float ald = alD[n * 4 + h];
  const __half* __restrict__ hb = h1h + h * 64 + l16 * 4;

  float4 A0 = make_float4(0.f,0.f,0.f,0.f), A1 = A0, A2 = A0, A3 = A0;
  float d0 = 0.f, d1 = 0.f, d2 = 0.f, d3 = 0.f;
  int i = start;
  for (; i + 3 < end; i += 4){
    int s0 = adjS[i],     s1 = adjS[i + 1];
    int s2 = adjS[i + 2], s3 = adjS[i + 3];
    float t0 = alS[s0 * 4 + h] + ald;
    float t1 = alS[s1 * 4 + h] + ald;
    float t2 = alS[s2 * 4 + h] + ald;
    float t3 = alS[s3 * 4 + h] + ald;
    t0 = (t0 > 0.f) ? t0 : NEG_SLOPE * t0;
    t1 = (t1 > 0.f) ? t1 : NEG_SLOPE * t1;
    t2 = (t2 > 0.f) ? t2 : NEG_SLOPE * t2;
    t3 = (t3 > 0.f) ? t3 : NEG_SLOPE * t3;
    float w0 = __expf(t0), w1 = __expf(t1), w2 = __expf(t2), w3 = __expf(t3);
    float2 r0 = *(const float2*)&hb[(size_t)s0 * 256];
    float2 r1 = *(const float2*)&hb[(size_t)s1 * 256];
    float2 r2 = *(const float2*)&hb[(size_t)s2 * 256];
    float2 r3 = *(const float2*)&hb[(size_t)s3 * 256];
    const __half2* p0 = (const __half2*)&r0;
    const __half2* p1 = (const __half2*)&r1;
    const __half2* p2 = (const __half2*)&r2;
    const __half2* p3 = (const __half2*)&r3;
    float2 v0a = __half22float2(p0[0]), v0b = __half22float2(p0[1]);
    float2 v1a = __half22float2(p1[0]), v1b = __half22float2(p1[1]);
    float2 v2a = __half22float2(p2[0]), v2b = __half22float2(p2[1]);
    float2 v3a = __half22float2(p3[0]), v3b = __half22float2(p3[1]);
    A0.x += w0 * v0a.x; A0.y += w0 * v0a.y; A0.z += w0 * v0b.x; A0.w += w0 * v0b.y;
    A1.x += w1 * v1a.x; A1.y += w1 * v1a.y; A1.z += w1 * v1b.x; A1.w += w1 * v1b.y;
    A2.x += w2 * v2a.x; A2.y += w2 * v2a.y; A2.z += w2 * v2b.x; A2.w += w2 * v2b.y;
    A3.x += w3 * v3a.x; A3.y += w3 * v3a.y; A3.z += w3 * v3b.x; A3.w += w3 * v3b.y;
    d0 += w0; d1 += w1; d2 += w2; d3 += w3;
  }
  for (; i < end; ++i){
    int s0 = adjS[i];
    float t0 = alS[s0 * 4 + h] + ald;
    t0 = (t0 > 0.f) ? t0 : NEG_SLOPE * t0;
    float w0 = __expf(t0);
    float2 r0 = *(const float2*)&hb[(size_t)s0 * 256];
    const __half2* p0 = (const __half2*)&r0;
    float2 v0a = __half22float2(p0[0]), v0b = __half22float2(p0[1]);
    A0.x += w0 * v0a.x; A0.y += w0 * v0a.y; A0.z += w0 * v0b.x; A0.w += w0 * v0b.y;
    d0 += w0;
  }
  float rinv = 1.f / (((d0 + d1) + (d2 + d3)) + 1e-16f);
  float4 bv = *(const float4*)&b1[h * 64 + l16 * 4];
  float4 o;
  o.x = ((A0.x + A1.x) + (A2.x + A3.x)) * rinv + bv.x;
  o.y = ((A0.y + A1.y) + (A2.y + A3.y)) * rinv + bv.y;
  o.z = ((A0.z + A1.z) + (A2.z + A3.z)) * rinv + bv.z;
  o.w = ((A0.w + A1.w) + (A2.w + A3.w)) * rinv + bv.w;
  o.x = (o.x > 0.f) ? o.x : (__expf(o.x) - 1.f);
  o.y = (o.y > 0.f) ? o.y : (__expf(o.y) - 1.f);
  o.z = (o.z > 0.f) ? o.z : (__expf(o.z) - 1.f);
  o.w = (o.w > 0.f) ? o.w : (__expf(o.w) - 1.f);
  union { __half2 h2[2]; float2 f2; } u;
  u.h2[0] = __floats2half2_rn(o.x, o.y);
  u.h2[1] = __floats2half2_rn(o.z, o.w);
  *(float2*)&heluh[(size_t)n * 256 + h * 64 + l16 * 4] = u.f2;
}

// ---- GEMM2 via MFMA fp16: h2 = helu @ W2 [20000,16] (pre-bias) + fused projections ----
__global__ __launch_bounds__(256) void k_gemm2(
                        const _Float16* __restrict__ heluh, const float* __restrict__ W2,
                        const float* __restrict__ as2, const float* __restrict__ ad2,
                        float* __restrict__ h2, float* __restrict__ alS, float* __restrict__ alD){
  __shared__ _Float16 Ht[64][264];   // [node][k], pad 8
  __shared__ _Float16 Wt[16][264];   // [col][k]
  int t = threadIdx.x;
  int n0 = blockIdx.x * 64;
  #pragma unroll
  for (int ii = 0; ii < 8; ++ii){
    int f = t + ii * 256;            // 2048 slots = 64 rows x 32 half8
    int r = f >> 5, s = f & 31;
    half8 v = (half8)(_Float16)0.f;
    if (n0 + r < N_NODES) v = *(const half8*)&heluh[(size_t)(n0 + r) * 256 + s * 8];
    *(half8*)&Ht[r][s * 8] = v;
  }
  {                                   // W2 [256 k][16 col] fp32 -> Wt[16][256] fp16
    int k = t;
    float4 w0 = *(const float4*)&W2[k * 16 + 0];
    float4 w1 = *(const float4*)&W2[k * 16 + 4];
    float4 w2 = *(const float4*)&W2[k * 16 + 8];
    float4 w3 = *(const float4*)&W2[k * 16 + 12];
    float wv[16] = {w0.x,w0.y,w0.z,w0.w, w1.x,w1.y,w1.z,w1.w,
                    w2.x,w2.y,w2.z,w2.w, w3.x,w3.y,w3.z,w3.w};
    #pragma unroll
    for (int c = 0; c < 16; ++c) Wt[c][k] = (_Float16)wv[c];
  }
  __syncthreads();

  int w = t >> 6, lane = t & 63;
  int g = lane >> 4, mi = lane & 15;
  f32x4 acc = {};
  #pragma unroll
  for (int kk = 0; kk < 8; ++kk){
    int ko = kk * 32 + g * 8;
    half8 b = *(const half8*)&Ht[w * 16 + mi][ko];
    half8 a = *(const half8*)&Wt[mi][ko];
    acc = __builtin_amdgcn_mfma_f32_16x16x32_f16(a, b, acc, 0, 0, 0);
  }
  int n = n0 + w * 16 + mi;
  float4 asv = *(const float4*)&as2[g * 4];
  float4 adv = *(const float4*)&ad2[g * 4];
  float s_ = acc[0] * asv.x + acc[1] * asv.y + acc[2] * asv.z + acc[3] * asv.w;
  float d_ = acc[0] * adv.x + acc[1] * adv.y + acc[2] * adv.z + acc[3] * adv.w;
  s_ += __shfl_xor(s_, 16); s_ += __shfl_xor(s_, 32);
  d_ += __shfl_xor(d_, 16); d_ += __shfl_xor(d_, 32);
  if (n < N_NODES){
    float4 hv = make_float4(acc[0], acc[1], acc[2], acc[3]);
    *(float4*)&h2[(size_t)n * 16 + g * 4] = hv;   // pre-bias
    if (g == 0){ alS[n] = s_; alD[n] = d_; }
  }
}

// ---- layer-2 single-pass softmax+aggregate+bias -> d_out. ----
__global__ __launch_bounds__(256) void k_attn2(
                        const int* __restrict__ cur, const int* __restrict__ adjS,
                        const float* __restrict__ h2,
                        const float* __restrict__ alS, const float* __restrict__ alD,
                        const float* __restrict__ b2, float* __restrict__ out){
  int t    = threadIdx.x;
  int w    = t >> 6, lane = t & 63;
  int grp  = lane >> 4, l16 = lane & 15;
  int j    = l16 >> 2, c4 = l16 & 3;
  int n    = blockIdx.x * 16 + w * 4 + grp;

  int cnt  = cur[n]; cnt = (cnt > MAXDEG) ? MAXDEG : cnt;
  int start = n * MAXDEG, end = start + cnt;
  float ald = alD[n];
  float4 acc = make_float4(0.f,0.f,0.f,0.f);
  float den = 0.f;
  for (int i = start + j; i < end; i += 4){
    int s = adjS[i];
    float tt = alS[s] + ald;
    tt = (tt > 0.f) ? tt : NEG_SLOPE * tt;
    float wv = __expf(tt);
    float4 v = *(const float4*)&h2[(size_t)s * 16 + c4 * 4];
    acc.x += wv * v.x; acc.y += wv * v.y; acc.z += wv * v.z; acc.w += wv * v.w;
    den += wv;
  }
  #pragma unroll
  for (int off = 4; off <= 8; off <<= 1){
    acc.x += __shfl_xor(acc.x, off);
    acc.y += __shfl_xor(acc.y, off);
    acc.z += __shfl_xor(acc.z, off);
    acc.w += __shfl_xor(acc.w, off);
    den   += __shfl_xor(den, off);
  }
  if (j == 0){
    float rinv = 1.f / (den + 1e-16f);
    float4 bv = *(const float4*)&b2[c4 * 4];
    float4 o;
    o.x = acc.x * rinv + bv.x; o.y = acc.y * rinv + bv.y;
    o.z = acc.z * rinv + bv.z; o.w = acc.w * rinv + bv.w;
    *(float4*)&out[(size_t)n * 16 + c4 * 4] = o;
  }
}

extern "C" void kernel_launch(void* const* d_in, const int* in_sizes, int n_in,
                              void* d_out, int out_size, void* d_ws, size_t ws_size,
                              hipStream_t stream){
  const float* x   = (const float*)d_in[0];
  const int*   ei  = (const int*)d_in[1];
  const float* W1  = (const float*)d_in[2];
  const float* as1 = (const float*)d_in[3];
  const float* ad1 = (const float*)d_in[4];
  const float* b1  = (const float*)d_in[5];
  const float* W2  = (const float*)d_in[6];
  const float* as2 = (const float*)d_in[7];
  const float* ad2 = (const float*)d_in[8];
  const float* b2  = (const float*)d_in[9];
  float* out = (float*)d_out;

  float* fws = (float*)d_ws;
  size_t off = 0;
  __half* h1h = (__half*)(fws + off); off += (size_t)N_NODES * 128;      // fp16 [20000,256]
  _Float16* xh  = (_Float16*)(fws + off); off += (size_t)N_NODES * 64;    // fp16 [20000,128]
  _Float16* W1t = (_Float16*)(fws + off); off += 256 * 64;                // fp16 [256,128]
  _Float16* heluh = (_Float16*)(fws + off); off += (size_t)N_NODES * 128; // fp16 [20000,256]
  float* h2   = fws + off; off += (size_t)N_NODES * 16;
  float* alS1 = fws + off; off += N_NODES * 4;
  float* alD1 = fws + off; off += N_NODES * 4;
  float* alS2 = fws + off; off += N_NODES;
  float* alD2 = fws + off; off += N_NODES;
  int* cur  = (int*)(fws + off); off += N_NODES;
  int* adjS = (int*)(fws + off); off += (size_t)N_NODES * MAXDEG;

  const int XW = N_NODES * N_FEAT / 8 + 4096;      // x-convert + W1t jobs
  const int PRE_N = (E_TOT > XW ? E_TOT : XW);

  k_zero<<<(N_NODES + 255) / 256, 256, 0, stream>>>(cur);
  k_pre<<<(PRE_N + 255) / 256, 256, 0, stream>>>(ei, cur, adjS, x, xh, W1, W1t);
  k_gemm1<<<dim3(313, 4), 256, 0, stream>>>(xh, W1t, as1, ad1, (_Float16*)h1h, alS1, alD1);
  k_attn1<<<5000, 256, 0, stream>>>(cur, adjS, h1h, alS1, alD1, b1, heluh);
  k_gemm2<<<313, 256, 0, stream>>>(heluh, W2, as2, ad2, h2, alS2, alD2);
  k_attn2<<<1250, 256, 0, stream>>>(cur, adjS, h2, alS2, alD2, b2, out);
}

// Round 11
// 80.148 us; speedup vs baseline: 1.2733x; 1.1368x over previous
//
#include <hip/hip_runtime.h>
#include <hip/hip_bf16.h>
#include <hip/hip_fp16.h>
#include <math.h>

#define N_NODES 20000
#define N_EDGES 320000
#define E_TOT   (N_EDGES + N_NODES)
#define N_FEAT  128
#define NEG_SLOPE 0.2f
#define MAXDEG  96   // padded adjacency stride; in-degree ~Binom mean 17, max ~45 << 96

typedef _Float16 half8 __attribute__((ext_vector_type(8)));
typedef float f32x4 __attribute__((ext_vector_type(4)));

// ---- init: zero cursor + x->fp16 convert + W1 fp16-transpose (all independent) ----
__global__ void k_init(int* __restrict__ cur,
                       const float* __restrict__ x, _Float16* __restrict__ xh,
                       const float* __restrict__ W1, _Float16* __restrict__ W1t){
  int tid = blockIdx.x * blockDim.x + threadIdx.x;
  if (tid < N_NODES) cur[tid] = 0;
  if (tid < (N_NODES * N_FEAT / 8)){           // 320000 chunks of 8
    float4 a = *(const float4*)&x[(size_t)tid * 8];
    float4 b = *(const float4*)&x[(size_t)tid * 8 + 4];
    union { __half2 h2[4]; half8 h8; } u;
    u.h2[0] = __floats2half2_rn(a.x, a.y);
    u.h2[1] = __floats2half2_rn(a.z, a.w);
    u.h2[2] = __floats2half2_rn(b.x, b.y);
    u.h2[3] = __floats2half2_rn(b.z, b.w);
    *(half8*)&xh[(size_t)tid * 8] = u.h8;
  }
  if (tid < 4096){                             // W1t[256 n][128 k]
    int n = tid >> 4, ks = tid & 15;
    union { __half2 h2[4]; half8 h8; } u;
    float v[8];
    #pragma unroll
    for (int r = 0; r < 8; ++r) v[r] = W1[(size_t)(ks * 8 + r) * 256 + n];
    u.h2[0] = __floats2half2_rn(v[0], v[1]);
    u.h2[1] = __floats2half2_rn(v[2], v[3]);
    u.h2[2] = __floats2half2_rn(v[4], v[5]);
    u.h2[3] = __floats2half2_rn(v[6], v[7]);
    *(half8*)&W1t[(size_t)n * 128 + ks * 8] = u.h8;
  }
}

// ---- GEMM1 via MFMA fp16 + adjacency build in prologue.
// Adj scatter atomics issue first and drain under the staging/MFMA work.
__global__ __launch_bounds__(256) void k_gemm1(
                        const _Float16* __restrict__ xh, const _Float16* __restrict__ W1t,
                        const float* __restrict__ as1, const float* __restrict__ ad1,
                        _Float16* __restrict__ h1h,
                        float* __restrict__ alS, float* __restrict__ alD,
                        const int* __restrict__ ei, int* __restrict__ cur,
                        int* __restrict__ adjS){
  __shared__ _Float16 xt[64][136];   // [m][k], pad 8 halves
  __shared__ _Float16 Wt[64][136];   // [n][k]
  int t  = threadIdx.x;

  // --- padded-adjacency build (grid-stride over all edges + self-loops) ---
  {
    int fb = blockIdx.y * 313 + blockIdx.x;
    int gtid = fb * 256 + t;
    const int GSZ = 313 * 4 * 256;   // 320512
    for (int e = gtid; e < E_TOT; e += GSZ){
      int s, d;
      if (e < N_EDGES){ s = ei[e]; d = ei[N_EDGES + e]; }
      else            { s = d = e - N_EDGES; }
      int pos = atomicAdd(&cur[d], 1);
      if (pos < MAXDEG) adjS[d * MAXDEG + pos] = s;
    }
  }

  int m0 = blockIdx.x * 64;
  int by = blockIdx.y;               // head
  int j0 = by * 64;
  #pragma unroll
  for (int ii = 0; ii < 4; ++ii){
    int f = t + ii * 256;            // 1024 slots = 64 rows x 16 half8
    int r = f >> 4, s = f & 15;
    half8 xv = (half8)(_Float16)0.f;
    if (m0 + r < N_NODES) xv = *(const half8*)&xh[(size_t)(m0 + r) * 128 + s * 8];
    *(half8*)&xt[r][s * 8] = xv;
    half8 wv = *(const half8*)&W1t[(size_t)(j0 + r) * 128 + s * 8];
    *(half8*)&Wt[r][s * 8] = wv;
  }
  __syncthreads();

  int w = t >> 6, lane = t & 63;
  int g = lane >> 4, mi = lane & 15;
  f32x4 acc[4] = {};
  #pragma unroll
  for (int kk = 0; kk < 4; ++kk){
    int ko = kk * 32 + g * 8;
    half8 b = *(const half8*)&xt[w * 16 + mi][ko];
    #pragma unroll
    for (int s = 0; s < 4; ++s){
      half8 a = *(const half8*)&Wt[s * 16 + mi][ko];
      acc[s] = __builtin_amdgcn_mfma_f32_16x16x32_f16(a, b, acc[s], 0, 0, 0);
    }
  }

  int m = m0 + w * 16 + mi;
  float s_ = 0.f, d_ = 0.f;
  #pragma unroll
  for (int s = 0; s < 4; ++s){
    int nb = j0 + s * 16 + g * 4;
    float4 asv = *(const float4*)&as1[nb];
    float4 adv = *(const float4*)&ad1[nb];
    s_ += acc[s][0] * asv.x + acc[s][1] * asv.y + acc[s][2] * asv.z + acc[s][3] * asv.w;
    d_ += acc[s][0] * adv.x + acc[s][1] * adv.y + acc[s][2] * adv.z + acc[s][3] * adv.w;
    if (m < N_NODES){
      union { __half2 h2[2]; float2 f2; } u;
      u.h2[0] = __floats2half2_rn(acc[s][0], acc[s][1]);
      u.h2[1] = __floats2half2_rn(acc[s][2], acc[s][3]);
      *(float2*)&h1h[(size_t)m * 256 + nb] = u.f2;
    }
  }
  s_ += __shfl_xor(s_, 16); s_ += __shfl_xor(s_, 32);
  d_ += __shfl_xor(d_, 16); d_ += __shfl_xor(d_, 32);
  if (g == 0 && m < N_NODES){ alS[m * 4 + by] = s_; alD[m * 4 + by] = d_; }
}

// ---- layer-1 single-pass softmax+aggregate+bias+ELU (fp16 gathers, 4-way ILP,
// int4 adjacency loads + next-quad prefetch). head = blockIdx&3 keeps each XCD's
// gather footprint to one 2.56MB head slice.
__global__ __launch_bounds__(256) void k_attn1(
                        const int* __restrict__ cur, const int* __restrict__ adjS,
                        const __half* __restrict__ h1h,
                        const float* __restrict__ alS, const float* __restrict__ alD,
                        const float* __restrict__ b1, _Float16* __restrict__ heluh){
  int b    = blockIdx.x;
  int slot = b & 7;
  int h    = slot & 3;
  int g    = (slot >> 2) * 625 + (b >> 3);    // node group [0,1250)
  int t    = threadIdx.x;
  int w    = t >> 6, lane = t & 63;
  int grp  = lane >> 4, l16 = lane & 15;
  int n    = g * 16 + w * 4 + grp;

  int cnt  = cur[n]; cnt = (cnt > MAXDEG) ? MAXDEG : cnt;
  int start = n * MAXDEG, end = start + cnt;
  float ald = alD[n * 4 + h];
  const __half* __restrict__ hb = h1h + h * 64 + l16 * 4;

  float4 A0 = make_float4(0.f,0.f,0.f,0.f), A1 = A0, A2 = A0, A3 = A0;
  float d0 = 0.f, d1 = 0.f, d2 = 0.f, d3 = 0.f;
  int i = start;
  if (i + 3 < end){
    int4 q = *(const int4*)&adjS[i];           // 16B-aligned (MAXDEG=96)
    while (i + 3 < end){
      int s0 = q.x, s1 = q.y, s2 = q.z, s3 = q.w;
      int inext = i + 4;
      if (inext + 3 < end) q = *(const int4*)&adjS[inext];   // prefetch next quad
      float t0 = alS[s0 * 4 + h] + ald;
      float t1 = alS[s1 * 4 + h] + ald;
      float t2 = alS[s2 * 4 + h] + ald;
      float t3 = alS[s3 * 4 + h] + ald;
      t0 = (t0 > 0.f) ? t0 : NEG_SLOPE * t0;
      t1 = (t1 > 0.f) ? t1 : NEG_SLOPE * t1;
      t2 = (t2 > 0.f) ? t2 : NEG_SLOPE * t2;
      t3 = (t3 > 0.f) ? t3 : NEG_SLOPE * t3;
      float w0 = __expf(t0), w1 = __expf(t1), w2 = __expf(t2), w3 = __expf(t3);
      float2 r0 = *(const float2*)&hb[(size_t)s0 * 256];
      float2 r1 = *(const float2*)&hb[(size_t)s1 * 256];
      float2 r2 = *(const float2*)&hb[(size_t)s2 * 256];
      float2 r3 = *(const float2*)&hb[(size_t)s3 * 256];
      const __half2* p0 = (const __half2*)&r0;
      const __half2* p1 = (const __half2*)&r1;
      const __half2* p2 = (const __half2*)&r2;
      const __half2* p3 = (const __half2*)&r3;
      float2 v0a = __half22float2(p0[0]), v0b = __half22float2(p0[1]);
      float2 v1a = __half22float2(p1[0]), v1b = __half22float2(p1[1]);
      float2 v2a = __half22float2(p2[0]), v2b = __half22float2(p2[1]);
      float2 v3a = __half22float2(p3[0]), v3b = __half22float2(p3[1]);
      A0.x += w0 * v0a.x; A0.y += w0 * v0a.y; A0.z += w0 * v0b.x; A0.w += w0 * v0b.y;
      A1.x += w1 * v1a.x; A1.y += w1 * v1a.y; A1.z += w1 * v1b.x; A1.w += w1 * v1b.y;
      A2.x += w2 * v2a.x; A2.y += w2 * v2a.y; A2.z += w2 * v2b.x; A2.w += w2 * v2b.y;
      A3.x += w3 * v3a.x; A3.y += w3 * v3a.y; A3.z += w3 * v3b.x; A3.w += w3 * v3b.y;
      d0 += w0; d1 += w1; d2 += w2; d3 += w3;
      i = inext;
    }
  }
  for (; i < end; ++i){
    int s0 = adjS[i];
    float t0 = alS[s0 * 4 + h] + ald;
    t0 = (t0 > 0.f) ? t0 : NEG_SLOPE * t0;
    float w0 = __expf(t0);
    float2 r0 = *(const float2*)&hb[(size_t)s0 * 256];
    const __half2* p0 = (const __half2*)&r0;
    float2 v0a = __half22float2(p0[0]), v0b = __half22float2(p0[1]);
    A0.x += w0 * v0a.x; A0.y += w0 * v0a.y; A0.z += w0 * v0b.x; A0.w += w0 * v0b.y;
    d0 += w0;
  }
  float rinv = 1.f / (((d0 + d1) + (d2 + d3)) + 1e-16f);
  float4 bv = *(const float4*)&b1[h * 64 + l16 * 4];
  float4 o;
  o.x = ((A0.x + A1.x) + (A2.x + A3.x)) * rinv + bv.x;
  o.y = ((A0.y + A1.y) + (A2.y + A3.y)) * rinv + bv.y;
  o.z = ((A0.z + A1.z) + (A2.z + A3.z)) * rinv + bv.z;
  o.w = ((A0.w + A1.w) + (A2.w + A3.w)) * rinv + bv.w;
  o.x = (o.x > 0.f) ? o.x : (__expf(o.x) - 1.f);
  o.y = (o.y > 0.f) ? o.y : (__expf(o.y) - 1.f);
  o.z = (o.z > 0.f) ? o.z : (__expf(o.z) - 1.f);
  o.w = (o.w > 0.f) ? o.w : (__expf(o.w) - 1.f);
  union { __half2 h2[2]; float2 f2; } u;
  u.h2[0] = __floats2half2_rn(o.x, o.y);
  u.h2[1] = __floats2half2_rn(o.z, o.w);
  *(float2*)&heluh[(size_t)n * 256 + h * 64 + l16 * 4] = u.f2;
}

// ---- GEMM2 via MFMA fp16: h2 = helu @ W2 [20000,16] (pre-bias) + fused projections ----
__global__ __launch_bounds__(256) void k_gemm2(
                        const _Float16* __restrict__ heluh, const float* __restrict__ W2,
                        const float* __restrict__ as2, const float* __restrict__ ad2,
                        float* __restrict__ h2, float* __restrict__ alS, float* __restrict__ alD){
  __shared__ _Float16 Ht[64][264];   // [node][k], pad 8
  __shared__ _Float16 Wt[16][264];   // [col][k]
  int t = threadIdx.x;
  int n0 = blockIdx.x * 64;
  #pragma unroll
  for (int ii = 0; ii < 8; ++ii){
    int f = t + ii * 256;            // 2048 slots = 64 rows x 32 half8
    int r = f >> 5, s = f & 31;
    half8 v = (half8)(_Float16)0.f;
    if (n0 + r < N_NODES) v = *(const half8*)&heluh[(size_t)(n0 + r) * 256 + s * 8];
    *(half8*)&Ht[r][s * 8] = v;
  }
  {                                   // W2 [256 k][16 col] fp32 -> Wt[16][256] fp16
    int k = t;
    float4 w0 = *(const float4*)&W2[k * 16 + 0];
    float4 w1 = *(const float4*)&W2[k * 16 + 4];
    float4 w2 = *(const float4*)&W2[k * 16 + 8];
    float4 w3 = *(const float4*)&W2[k * 16 + 12];
    float wv[16] = {w0.x,w0.y,w0.z,w0.w, w1.x,w1.y,w1.z,w1.w,
                    w2.x,w2.y,w2.z,w2.w, w3.x,w3.y,w3.z,w3.w};
    #pragma unroll
    for (int c = 0; c < 16; ++c) Wt[c][k] = (_Float16)wv[c];
  }
  __syncthreads();

  int w = t >> 6, lane = t & 63;
  int g = lane >> 4, mi = lane & 15;
  f32x4 acc = {};
  #pragma unroll
  for (int kk = 0; kk < 8; ++kk){
    int ko = kk * 32 + g * 8;
    half8 b = *(const half8*)&Ht[w * 16 + mi][ko];
    half8 a = *(const half8*)&Wt[mi][ko];
    acc = __builtin_amdgcn_mfma_f32_16x16x32_f16(a, b, acc, 0, 0, 0);
  }
  int n = n0 + w * 16 + mi;
  float4 asv = *(const float4*)&as2[g * 4];
  float4 adv = *(const float4*)&ad2[g * 4];
  float s_ = acc[0] * asv.x + acc[1] * asv.y + acc[2] * asv.z + acc[3] * asv.w;
  float d_ = acc[0] * adv.x + acc[1] * adv.y + acc[2] * adv.z + acc[3] * adv.w;
  s_ += __shfl_xor(s_, 16); s_ += __shfl_xor(s_, 32);
  d_ += __shfl_xor(d_, 16); d_ += __shfl_xor(d_, 32);
  if (n < N_NODES){
    float4 hv = make_float4(acc[0], acc[1], acc[2], acc[3]);
    *(float4*)&h2[(size_t)n * 16 + g * 4] = hv;   // pre-bias
    if (g == 0){ alS[n] = s_; alD[n] = d_; }
  }
}

// ---- layer-2 single-pass softmax+aggregate+bias -> d_out. ----
__global__ __launch_bounds__(256) void k_attn2(
                        const int* __restrict__ cur, const int* __restrict__ adjS,
                        const float* __restrict__ h2,
                        const float* __restrict__ alS, const float* __restrict__ alD,
                        const float* __restrict__ b2, float* __restrict__ out){
  int t    = threadIdx.x;
  int w    = t >> 6, lane = t & 63;
  int grp  = lane >> 4, l16 = lane & 15;
  int j    = l16 >> 2, c4 = l16 & 3;
  int n    = blockIdx.x * 16 + w * 4 + grp;

  int cnt  = cur[n]; cnt = (cnt > MAXDEG) ? MAXDEG : cnt;
  int start = n * MAXDEG, end = start + cnt;
  float ald = alD[n];
  float4 acc = make_float4(0.f,0.f,0.f,0.f);
  float den = 0.f;
  for (int i = start + j; i < end; i += 4){
    int s = adjS[i];
    float tt = alS[s] + ald;
    tt = (tt > 0.f) ? tt : NEG_SLOPE * tt;
    float wv = __expf(tt);
    float4 v = *(const float4*)&h2[(size_t)s * 16 + c4 * 4];
    acc.x += wv * v.x; acc.y += wv * v.y; acc.z += wv * v.z; acc.w += wv * v.w;
    den += wv;
  }
  #pragma unroll
  for (int off = 4; off <= 8; off <<= 1){
    acc.x += __shfl_xor(acc.x, off);
    acc.y += __shfl_xor(acc.y, off);
    acc.z += __shfl_xor(acc.z, off);
    acc.w += __shfl_xor(acc.w, off);
    den   += __shfl_xor(den, off);
  }
  if (j == 0){
    float rinv = 1.f / (den + 1e-16f);
    float4 bv = *(const float4*)&b2[c4 * 4];
    float4 o;
    o.x = acc.x * rinv + bv.x; o.y = acc.y * rinv + bv.y;
    o.z = acc.z * rinv + bv.z; o.w = acc.w * rinv + bv.w;
    *(float4*)&out[(size_t)n * 16 + c4 * 4] = o;
  }
}

extern "C" void kernel_launch(void* const* d_in, const int* in_sizes, int n_in,
                              void* d_out, int out_size, void* d_ws, size_t ws_size,
                              hipStream_t stream){
  const float* x   = (const float*)d_in[0];
  const int*   ei  = (const int*)d_in[1];
  const float* W1  = (const float*)d_in[2];
  const float* as1 = (const float*)d_in[3];
  const float* ad1 = (const float*)d_in[4];
  const float* b1  = (const float*)d_in[5];
  const float* W2  = (const float*)d_in[6];
  const float* as2 = (const float*)d_in[7];
  const float* ad2 = (const float*)d_in[8];
  const float* b2  = (const float*)d_in[9];
  float* out = (float*)d_out;

  float* fws = (float*)d_ws;
  size_t off = 0;
  __half* h1h = (__half*)(fws + off); off += (size_t)N_NODES * 128;      // fp16 [20000,256]
  _Float16* xh  = (_Float16*)(fws + off); off += (size_t)N_NODES * 64;    // fp16 [20000,128]
  _Float16* W1t = (_Float16*)(fws + off); off += 256 * 64;                // fp16 [256,128]
  _Float16* heluh = (_Float16*)(fws + off); off += (size_t)N_NODES * 128; // fp16 [20000,256]
  float* h2   = fws + off; off += (size_t)N_NODES * 16;
  float* alS1 = fws + off; off += N_NODES * 4;
  float* alD1 = fws + off; off += N_NODES * 4;
  float* alS2 = fws + off; off += N_NODES;
  float* alD2 = fws + off; off += N_NODES;
  int* cur  = (int*)(fws + off); off += N_NODES;
  int* adjS = (int*)(fws + off); off += (size_t)N_NODES * MAXDEG;

  k_init<<<(N_NODES * N_FEAT / 8 + 255) / 256, 256, 0, stream>>>(cur, x, xh, W1, W1t);
  k_gemm1<<<dim3(313, 4), 256, 0, stream>>>(xh, W1t, as1, ad1, (_Float16*)h1h,
                                            alS1, alD1, ei, cur, adjS);
  k_attn1<<<5000, 256, 0, stream>>>(cur, adjS, h1h, alS1, alD1, b1, heluh);
  k_gemm2<<<313, 256, 0, stream>>>(heluh, W2, as2, ad2, h2, alS2, alD2);
  k_attn2<<<1250, 256, 0, stream>>>(cur, adjS, h2, alS2, alD2, b2, out);
}

// Round 12
// 78.215 us; speedup vs baseline: 1.3048x; 1.0247x over previous
//
#include <hip/hip_runtime.h>
#include <hip/hip_bf16.h>
#include <hip/hip_fp16.h>
#include <math.h>

#define N_NODES 20000
#define N_EDGES 320000
#define E_TOT   (N_EDGES + N_NODES)
#define N_FEAT  128
#define NEG_SLOPE 0.2f
#define MAXDEG  96   // padded adjacency stride; in-degree ~Binom mean 17, max ~45 << 96

typedef _Float16 half8 __attribute__((ext_vector_type(8)));
typedef float f32x4 __attribute__((ext_vector_type(4)));

// ---- init: zero cursor + W1 fp16-transpose (x converts inside gemm1 now) ----
__global__ void k_init(int* __restrict__ cur,
                       const float* __restrict__ W1, _Float16* __restrict__ W1t){
  int tid = blockIdx.x * blockDim.x + threadIdx.x;
  if (tid < N_NODES) cur[tid] = 0;
  if (tid < 4096){                             // W1t[256 n][128 k]
    int n = tid >> 4, ks = tid & 15;
    union { __half2 h2[4]; half8 h8; } u;
    float v[8];
    #pragma unroll
    for (int r = 0; r < 8; ++r) v[r] = W1[(size_t)(ks * 8 + r) * 256 + n];
    u.h2[0] = __floats2half2_rn(v[0], v[1]);
    u.h2[1] = __floats2half2_rn(v[2], v[3]);
    u.h2[2] = __floats2half2_rn(v[4], v[5]);
    u.h2[3] = __floats2half2_rn(v[6], v[7]);
    *(half8*)&W1t[(size_t)n * 128 + ks * 8] = u.h8;
  }
}

// ---- GEMM1 via MFMA fp16 (stages x fp32->fp16 in-register) + adjacency build ----
__global__ __launch_bounds__(256) void k_gemm1(
                        const float* __restrict__ x, const _Float16* __restrict__ W1t,
                        const float* __restrict__ as1, const float* __restrict__ ad1,
                        _Float16* __restrict__ h1h,
                        float* __restrict__ alS, float* __restrict__ alD,
                        const int* __restrict__ ei, int* __restrict__ cur,
                        int* __restrict__ adjS){
  __shared__ _Float16 xt[64][136];   // [m][k], pad 8 halves
  __shared__ _Float16 Wt[64][136];   // [n][k]
  int t  = threadIdx.x;

  // --- padded-adjacency build (grid-stride over all edges + self-loops) ---
  {
    int fb = blockIdx.y * 313 + blockIdx.x;
    int gtid = fb * 256 + t;
    const int GSZ = 313 * 4 * 256;   // 320512
    for (int e = gtid; e < E_TOT; e += GSZ){
      int s, d;
      if (e < N_EDGES){ s = ei[e]; d = ei[N_EDGES + e]; }
      else            { s = d = e - N_EDGES; }
      int pos = atomicAdd(&cur[d], 1);
      if (pos < MAXDEG) adjS[d * MAXDEG + pos] = s;
    }
  }

  int m0 = blockIdx.x * 64;
  int by = blockIdx.y;               // head
  int j0 = by * 64;
  #pragma unroll
  for (int ii = 0; ii < 4; ++ii){
    int f = t + ii * 256;            // 1024 slots = 64 rows x 16 half8
    int r = f >> 4, s = f & 15;
    half8 xv = (half8)(_Float16)0.f;
    if (m0 + r < N_NODES){
      float4 a = *(const float4*)&x[(size_t)(m0 + r) * 128 + s * 8];
      float4 bq = *(const float4*)&x[(size_t)(m0 + r) * 128 + s * 8 + 4];
      union { __half2 h2[4]; half8 h8; } u;
      u.h2[0] = __floats2half2_rn(a.x, a.y);
      u.h2[1] = __floats2half2_rn(a.z, a.w);
      u.h2[2] = __floats2half2_rn(bq.x, bq.y);
      u.h2[3] = __floats2half2_rn(bq.z, bq.w);
      xv = u.h8;
    }
    *(half8*)&xt[r][s * 8] = xv;
    half8 wv = *(const half8*)&W1t[(size_t)(j0 + r) * 128 + s * 8];
    *(half8*)&Wt[r][s * 8] = wv;
  }
  __syncthreads();

  int w = t >> 6, lane = t & 63;
  int g = lane >> 4, mi = lane & 15;
  f32x4 acc[4] = {};
  #pragma unroll
  for (int kk = 0; kk < 4; ++kk){
    int ko = kk * 32 + g * 8;
    half8 b = *(const half8*)&xt[w * 16 + mi][ko];
    #pragma unroll
    for (int s = 0; s < 4; ++s){
      half8 a = *(const half8*)&Wt[s * 16 + mi][ko];
      acc[s] = __builtin_amdgcn_mfma_f32_16x16x32_f16(a, b, acc[s], 0, 0, 0);
    }
  }

  int m = m0 + w * 16 + mi;
  float s_ = 0.f, d_ = 0.f;
  #pragma unroll
  for (int s = 0; s < 4; ++s){
    int nb = j0 + s * 16 + g * 4;
    float4 asv = *(const float4*)&as1[nb];
    float4 adv = *(const float4*)&ad1[nb];
    s_ += acc[s][0] * asv.x + acc[s][1] * asv.y + acc[s][2] * asv.z + acc[s][3] * asv.w;
    d_ += acc[s][0] * adv.x + acc[s][1] * adv.y + acc[s][2] * adv.z + acc[s][3] * adv.w;
    if (m < N_NODES){
      union { __half2 h2[2]; float2 f2; } u;
      u.h2[0] = __floats2half2_rn(acc[s][0], acc[s][1]);
      u.h2[1] = __floats2half2_rn(acc[s][2], acc[s][3]);
      *(float2*)&h1h[(size_t)m * 256 + nb] = u.f2;
    }
  }
  s_ += __shfl_xor(s_, 16); s_ += __shfl_xor(s_, 32);
  d_ += __shfl_xor(d_, 16); d_ += __shfl_xor(d_, 32);
  if (g == 0 && m < N_NODES){ alS[m * 4 + by] = s_; alD[m * 4 + by] = d_; }
}

// ---- layer-1 single-pass softmax+aggregate+bias+ELU.
// 16-lane group = (node,head), split into TWO 8-lane halves on alternate edge
// quads; each lane owns 8 channels via one half8 (16B) gather -> wave-level
// VMEM count halves vs 8B/lane. Merge halves with shfl_xor(8).
// head = blockIdx&7-slot keeps each XCD's gather footprint to one 2.56MB slice.
__global__ __launch_bounds__(256) void k_attn1(
                        const int* __restrict__ cur, const int* __restrict__ adjS,
                        const __half* __restrict__ h1h,
                        const float* __restrict__ alS, const float* __restrict__ alD,
                        const float* __restrict__ b1, _Float16* __restrict__ heluh){
  int b    = blockIdx.x;
  int slot = b & 7;
  int h    = slot & 3;
  int g    = (slot >> 2) * 625 + (b >> 3);    // node group [0,1250)
  int t    = threadIdx.x;
  int w    = t >> 6, lane = t & 63;
  int grp  = lane >> 4, l16 = lane & 15;
  int hf   = l16 >> 3, l8 = l16 & 7;
  int n    = g * 16 + w * 4 + grp;

  int cnt  = cur[n]; cnt = (cnt > MAXDEG) ? MAXDEG : cnt;
  int base = n * MAXDEG;
  float ald = alD[n * 4 + h];
  const __half* __restrict__ hb = h1h + h * 64 + l8 * 8;

  float4 Aa = make_float4(0.f,0.f,0.f,0.f), Ab = Aa;
  float den = 0.f;

  int nq = cnt >> 2;
  for (int q = hf; q < nq; q += 2){
    int4 quad = *(const int4*)&adjS[base + q * 4];   // 16B-aligned
    int s0 = quad.x, s1 = quad.y, s2 = quad.z, s3 = quad.w;
    float t0 = alS[s0 * 4 + h] + ald;
    float t1 = alS[s1 * 4 + h] + ald;
    float t2 = alS[s2 * 4 + h] + ald;
    float t3 = alS[s3 * 4 + h] + ald;
    t0 = (t0 > 0.f) ? t0 : NEG_SLOPE * t0;
    t1 = (t1 > 0.f) ? t1 : NEG_SLOPE * t1;
    t2 = (t2 > 0.f) ? t2 : NEG_SLOPE * t2;
    t3 = (t3 > 0.f) ? t3 : NEG_SLOPE * t3;
    float w0 = __expf(t0), w1 = __expf(t1), w2 = __expf(t2), w3 = __expf(t3);
    float4 r0 = *(const float4*)&hb[(size_t)s0 * 256];
    float4 r1 = *(const float4*)&hb[(size_t)s1 * 256];
    float4 r2 = *(const float4*)&hb[(size_t)s2 * 256];
    float4 r3 = *(const float4*)&hb[(size_t)s3 * 256];
    const __half2* p0 = (const __half2*)&r0;
    const __half2* p1 = (const __half2*)&r1;
    const __half2* p2 = (const __half2*)&r2;
    const __half2* p3 = (const __half2*)&r3;
    {
      float2 a0 = __half22float2(p0[0]), a1 = __half22float2(p0[1]);
      float2 a2 = __half22float2(p0[2]), a3 = __half22float2(p0[3]);
      Aa.x += w0 * a0.x; Aa.y += w0 * a0.y; Aa.z += w0 * a1.x; Aa.w += w0 * a1.y;
      Ab.x += w0 * a2.x; Ab.y += w0 * a2.y; Ab.z += w0 * a3.x; Ab.w += w0 * a3.y;
    }
    {
      float2 a0 = __half22float2(p1[0]), a1 = __half22float2(p1[1]);
      float2 a2 = __half22float2(p1[2]), a3 = __half22float2(p1[3]);
      Aa.x += w1 * a0.x; Aa.y += w1 * a0.y; Aa.z += w1 * a1.x; Aa.w += w1 * a1.y;
      Ab.x += w1 * a2.x; Ab.y += w1 * a2.y; Ab.z += w1 * a3.x; Ab.w += w1 * a3.y;
    }
    {
      float2 a0 = __half22float2(p2[0]), a1 = __half22float2(p2[1]);
      float2 a2 = __half22float2(p2[2]), a3 = __half22float2(p2[3]);
      Aa.x += w2 * a0.x; Aa.y += w2 * a0.y; Aa.z += w2 * a1.x; Aa.w += w2 * a1.y;
      Ab.x += w2 * a2.x; Ab.y += w2 * a2.y; Ab.z += w2 * a3.x; Ab.w += w2 * a3.y;
    }
    {
      float2 a0 = __half22float2(p3[0]), a1 = __half22float2(p3[1]);
      float2 a2 = __half22float2(p3[2]), a3 = __half22float2(p3[3]);
      Aa.x += w3 * a0.x; Aa.y += w3 * a0.y; Aa.z += w3 * a1.x; Aa.w += w3 * a1.y;
      Ab.x += w3 * a2.x; Ab.y += w3 * a2.y; Ab.z += w3 * a3.x; Ab.w += w3 * a3.y;
    }
    den += ((w0 + w1) + (w2 + w3));
  }
  // tail (rem < 4 edges) handled by the half matching nq's parity
  if ((nq & 1) == hf){
    for (int i = base + nq * 4; i < base + cnt; ++i){
      int s0 = adjS[i];
      float t0 = alS[s0 * 4 + h] + ald;
      t0 = (t0 > 0.f) ? t0 : NEG_SLOPE * t0;
      float w0 = __expf(t0);
      float4 r0 = *(const float4*)&hb[(size_t)s0 * 256];
      const __half2* p0 = (const __half2*)&r0;
      float2 a0 = __half22float2(p0[0]), a1 = __half22float2(p0[1]);
      float2 a2 = __half22float2(p0[2]), a3 = __half22float2(p0[3]);
      Aa.x += w0 * a0.x; Aa.y += w0 * a0.y; Aa.z += w0 * a1.x; Aa.w += w0 * a1.y;
      Ab.x += w0 * a2.x; Ab.y += w0 * a2.y; Ab.z += w0 * a3.x; Ab.w += w0 * a3.y;
      den += w0;
    }
  }
  // merge the two halves
  Aa.x += __shfl_xor(Aa.x, 8); Aa.y += __shfl_xor(Aa.y, 8);
  Aa.z += __shfl_xor(Aa.z, 8); Aa.w += __shfl_xor(Aa.w, 8);
  Ab.x += __shfl_xor(Ab.x, 8); Ab.y += __shfl_xor(Ab.y, 8);
  Ab.z += __shfl_xor(Ab.z, 8); Ab.w += __shfl_xor(Ab.w, 8);
  den  += __shfl_xor(den, 8);

  if (hf == 0){
    float rinv = 1.f / (den + 1e-16f);
    float4 bv0 = *(const float4*)&b1[h * 64 + l8 * 8];
    float4 bv1 = *(const float4*)&b1[h * 64 + l8 * 8 + 4];
    float o0 = Aa.x * rinv + bv0.x;
    float o1 = Aa.y * rinv + bv0.y;
    float o2 = Aa.z * rinv + bv0.z;
    float o3 = Aa.w * rinv + bv0.w;
    float o4 = Ab.x * rinv + bv1.x;
    float o5 = Ab.y * rinv + bv1.y;
    float o6 = Ab.z * rinv + bv1.z;
    float o7 = Ab.w * rinv + bv1.w;
    o0 = (o0 > 0.f) ? o0 : (__expf(o0) - 1.f);
    o1 = (o1 > 0.f) ? o1 : (__expf(o1) - 1.f);
    o2 = (o2 > 0.f) ? o2 : (__expf(o2) - 1.f);
    o3 = (o3 > 0.f) ? o3 : (__expf(o3) - 1.f);
    o4 = (o4 > 0.f) ? o4 : (__expf(o4) - 1.f);
    o5 = (o5 > 0.f) ? o5 : (__expf(o5) - 1.f);
    o6 = (o6 > 0.f) ? o6 : (__expf(o6) - 1.f);
    o7 = (o7 > 0.f) ? o7 : (__expf(o7) - 1.f);
    union { __half2 h2[4]; half8 h8; } u;
    u.h2[0] = __floats2half2_rn(o0, o1);
    u.h2[1] = __floats2half2_rn(o2, o3);
    u.h2[2] = __floats2half2_rn(o4, o5);
    u.h2[3] = __floats2half2_rn(o6, o7);
    *(half8*)&heluh[(size_t)n * 256 + h * 64 + l8 * 8] = u.h8;
  }
}

// ---- GEMM2 via MFMA fp16: h2 = helu @ W2 [20000,16] (pre-bias) + fused projections ----
__global__ __launch_bounds__(256) void k_gemm2(
                        const _Float16* __restrict__ heluh, const float* __restrict__ W2,
                        const float* __restrict__ as2, const float* __restrict__ ad2,
                        float* __restrict__ h2, float* __restrict__ alS, float* __restrict__ alD){
  __shared__ _Float16 Ht[64][264];   // [node][k], pad 8
  __shared__ _Float16 Wt[16][264];   // [col][k]
  int t = threadIdx.x;
  int n0 = blockIdx.x * 64;
  #pragma unroll
  for (int ii = 0; ii < 8; ++ii){
    int f = t + ii * 256;            // 2048 slots = 64 rows x 32 half8
    int r = f >> 5, s = f & 31;
    half8 v = (half8)(_Float16)0.f;
    if (n0 + r < N_NODES) v = *(const half8*)&heluh[(size_t)(n0 + r) * 256 + s * 8];
    *(half8*)&Ht[r][s * 8] = v;
  }
  {                                   // W2 [256 k][16 col] fp32 -> Wt[16][256] fp16
    int k = t;
    float4 w0 = *(const float4*)&W2[k * 16 + 0];
    float4 w1 = *(const float4*)&W2[k * 16 + 4];
    float4 w2 = *(const float4*)&W2[k * 16 + 8];
    float4 w3 = *(const float4*)&W2[k * 16 + 12];
    float wv[16] = {w0.x,w0.y,w0.z,w0.w, w1.x,w1.y,w1.z,w1.w,
                    w2.x,w2.y,w2.z,w2.w, w3.x,w3.y,w3.z,w3.w};
    #pragma unroll
    for (int c = 0; c < 16; ++c) Wt[c][k] = (_Float16)wv[c];
  }
  __syncthreads();

  int w = t >> 6, lane = t & 63;
  int g = lane >> 4, mi = lane & 15;
  f32x4 acc = {};
  #pragma unroll
  for (int kk = 0; kk < 8; ++kk){
    int ko = kk * 32 + g * 8;
    half8 b = *(const half8*)&Ht[w * 16 + mi][ko];
    half8 a = *(const half8*)&Wt[mi][ko];
    acc = __builtin_amdgcn_mfma_f32_16x16x32_f16(a, b, acc, 0, 0, 0);
  }
  int n = n0 + w * 16 + mi;
  float4 asv = *(const float4*)&as2[g * 4];
  float4 adv = *(const float4*)&ad2[g * 4];
  float s_ = acc[0] * asv.x + acc[1] * asv.y + acc[2] * asv.z + acc[3] * asv.w;
  float d_ = acc[0] * adv.x + acc[1] * adv.y + acc[2] * adv.z + acc[3] * adv.w;
  s_ += __shfl_xor(s_, 16); s_ += __shfl_xor(s_, 32);
  d_ += __shfl_xor(d_, 16); d_ += __shfl_xor(d_, 32);
  if (n < N_NODES){
    float4 hv = make_float4(acc[0], acc[1], acc[2], acc[3]);
    *(float4*)&h2[(size_t)n * 16 + g * 4] = hv;   // pre-bias
    if (g == 0){ alS[n] = s_; alD[n] = d_; }
  }
}

// ---- layer-2 single-pass softmax+aggregate+bias -> d_out. ----
__global__ __launch_bounds__(256) void k_attn2(
                        const int* __restrict__ cur, const int* __restrict__ adjS,
                        const float* __restrict__ h2,
                        const float* __restrict__ alS, const float* __restrict__ alD,
                        const float* __restrict__ b2, float* __restrict__ out){
  int t    = threadIdx.x;
  int w    = t >> 6, lane = t & 63;
  int grp  = lane >> 4, l16 = lane & 15;
  int j    = l16 >> 2, c4 = l16 & 3;
  int n    = blockIdx.x * 16 + w * 4 + grp;

  int cnt  = cur[n]; cnt = (cnt > MAXDEG) ? MAXDEG : cnt;
  int start = n * MAXDEG, end = start + cnt;
  float ald = alD[n];
  float4 acc = make_float4(0.f,0.f,0.f,0.f);
  float den = 0.f;
  for (int i = start + j; i < end; i += 4){
    int s = adjS[i];
    float tt = alS[s] + ald;
    tt = (tt > 0.f) ? tt : NEG_SLOPE * tt;
    float wv = __expf(tt);
    float4 v = *(const float4*)&h2[(size_t)s * 16 + c4 * 4];
    acc.x += wv * v.x; acc.y += wv * v.y; acc.z += wv * v.z; acc.w += wv * v.w;
    den += wv;
  }
  #pragma unroll
  for (int off = 4; off <= 8; off <<= 1){
    acc.x += __shfl_xor(acc.x, off);
    acc.y += __shfl_xor(acc.y, off);
    acc.z += __shfl_xor(acc.z, off);
    acc.w += __shfl_xor(acc.w, off);
    den   += __shfl_xor(den, off);
  }
  if (j == 0){
    float rinv = 1.f / (den + 1e-16f);
    float4 bv = *(const float4*)&b2[c4 * 4];
    float4 o;
    o.x = acc.x * rinv + bv.x; o.y = acc.y * rinv + bv.y;
    o.z = acc.z * rinv + bv.z; o.w = acc.w * rinv + bv.w;
    *(float4*)&out[(size_t)n * 16 + c4 * 4] = o;
  }
}

extern "C" void kernel_launch(void* const* d_in, const int* in_sizes, int n_in,
                              void* d_out, int out_size, void* d_ws, size_t ws_size,
                              hipStream_t stream){
  const float* x   = (const float*)d_in[0];
  const int*   ei  = (const int*)d_in[1];
  const float* W1  = (const float*)d_in[2];
  const float* as1 = (const float*)d_in[3];
  const float* ad1 = (const float*)d_in[4];
  const float* b1  = (const float*)d_in[5];
  const float* W2  = (const float*)d_in[6];
  const float* as2 = (const float*)d_in[7];
  const float* ad2 = (const float*)d_in[8];
  const float* b2  = (const float*)d_in[9];
  float* out = (float*)d_out;

  float* fws = (float*)d_ws;
  size_t off = 0;
  __half* h1h = (__half*)(fws + off); off += (size_t)N_NODES * 128;      // fp16 [20000,256]
  _Float16* W1t = (_Float16*)(fws + off); off += 256 * 64;                // fp16 [256,128]
  _Float16* heluh = (_Float16*)(fws + off); off += (size_t)N_NODES * 128; // fp16 [20000,256]
  float* h2   = fws + off; off += (size_t)N_NODES * 16;
  float* alS1 = fws + off; off += N_NODES * 4;
  float* alD1 = fws + off; off += N_NODES * 4;
  float* alS2 = fws + off; off += N_NODES;
  float* alD2 = fws + off; off += N_NODES;
  int* cur  = (int*)(fws + off); off += N_NODES;
  int* adjS = (int*)(fws + off); off += (size_t)N_NODES * MAXDEG;

  k_init<<<(N_NODES + 255) / 256, 256, 0, stream>>>(cur, W1, W1t);
  k_gemm1<<<dim3(313, 4), 256, 0, stream>>>(x, W1t, as1, ad1, (_Float16*)h1h,
                                            alS1, alD1, ei, cur, adjS);
  k_attn1<<<5000, 256, 0, stream>>>(cur, adjS, h1h, alS1, alD1, b1, heluh);
  k_gemm2<<<313, 256, 0, stream>>>(heluh, W2, as2, ad2, h2, alS2, alD2);
  k_attn2<<<1250, 256, 0, stream>>>(cur, adjS, h2, alS2, alD2, b2, out);
}

// Round 13
// 76.303 us; speedup vs baseline: 1.3375x; 1.0251x over previous
//
#include <hip/hip_runtime.h>
#include <hip/hip_bf16.h>
#include <hip/hip_fp16.h>
#include <math.h>

#define N_NODES 20000
#define N_EDGES 320000
#define E_TOT   (N_EDGES + N_NODES)
#define N_FEAT  128
#define NEG_SLOPE 0.2f
#define MAXDEG  96   // padded adjacency stride; in-degree ~Binom mean 17, max ~45 << 96

typedef _Float16 half8 __attribute__((ext_vector_type(8)));
typedef float f32x4 __attribute__((ext_vector_type(4)));

// ---- init: zero cursor + W1 fp16-transpose ----
__global__ void k_init(int* __restrict__ cur,
                       const float* __restrict__ W1, _Float16* __restrict__ W1t){
  int tid = blockIdx.x * blockDim.x + threadIdx.x;
  if (tid < N_NODES) cur[tid] = 0;
  if (tid < 4096){                             // W1t[256 n][128 k]
    int n = tid >> 4, ks = tid & 15;
    union { __half2 h2[4]; half8 h8; } u;
    float v[8];
    #pragma unroll
    for (int r = 0; r < 8; ++r) v[r] = W1[(size_t)(ks * 8 + r) * 256 + n];
    u.h2[0] = __floats2half2_rn(v[0], v[1]);
    u.h2[1] = __floats2half2_rn(v[2], v[3]);
    u.h2[2] = __floats2half2_rn(v[4], v[5]);
    u.h2[3] = __floats2half2_rn(v[6], v[7]);
    *(half8*)&W1t[(size_t)n * 128 + ks * 8] = u.h8;
  }
}

// ---- GEMM1 via MFMA fp16, 2 HEADS PER BLOCK (x staged once per 2 heads) + adj build ----
__global__ __launch_bounds__(256) void k_gemm1(
                        const float* __restrict__ x, const _Float16* __restrict__ W1t,
                        const float* __restrict__ as1, const float* __restrict__ ad1,
                        _Float16* __restrict__ h1h,
                        float* __restrict__ alS, float* __restrict__ alD,
                        const int* __restrict__ ei, int* __restrict__ cur,
                        int* __restrict__ adjS){
  __shared__ _Float16 xt[64][136];    // [m][k], pad 8 halves
  __shared__ _Float16 Wt[128][136];   // [n][k] for 2 heads
  int t  = threadIdx.x;

  // --- padded-adjacency build (grid-stride over all edges + self-loops) ---
  {
    int fb = blockIdx.y * 313 + blockIdx.x;
    int gtid = fb * 256 + t;
    const int GSZ = 313 * 2 * 256;   // 160256
    for (int e = gtid; e < E_TOT; e += GSZ){
      int s, d;
      if (e < N_EDGES){ s = ei[e]; d = ei[N_EDGES + e]; }
      else            { s = d = e - N_EDGES; }
      int pos = atomicAdd(&cur[d], 1);
      if (pos < MAXDEG) adjS[d * MAXDEG + pos] = s;
    }
  }

  int m0 = blockIdx.x * 64;
  int by = blockIdx.y;               // head pair: heads 2*by, 2*by+1
  int j0 = by * 128;
  #pragma unroll
  for (int ii = 0; ii < 4; ++ii){
    int f = t + ii * 256;            // 1024 slots = 64 rows x 16 half8
    int r = f >> 4, s = f & 15;
    half8 xv = (half8)(_Float16)0.f;
    if (m0 + r < N_NODES){
      float4 a = *(const float4*)&x[(size_t)(m0 + r) * 128 + s * 8];
      float4 bq = *(const float4*)&x[(size_t)(m0 + r) * 128 + s * 8 + 4];
      union { __half2 h2[4]; half8 h8; } u;
      u.h2[0] = __floats2half2_rn(a.x, a.y);
      u.h2[1] = __floats2half2_rn(a.z, a.w);
      u.h2[2] = __floats2half2_rn(bq.x, bq.y);
      u.h2[3] = __floats2half2_rn(bq.z, bq.w);
      xv = u.h8;
    }
    *(half8*)&xt[r][s * 8] = xv;
  }
  #pragma unroll
  for (int ii = 0; ii < 8; ++ii){
    int f = t + ii * 256;            // 2048 slots = 128 rows x 16 half8
    int r = f >> 4, s = f & 15;
    half8 wv = *(const half8*)&W1t[(size_t)(j0 + r) * 128 + s * 8];
    *(half8*)&Wt[r][s * 8] = wv;
  }
  __syncthreads();

  int w = t >> 6, lane = t & 63;
  int g = lane >> 4, mi = lane & 15;
  f32x4 acc[8] = {};
  #pragma unroll
  for (int kk = 0; kk < 4; ++kk){
    int ko = kk * 32 + g * 8;
    half8 b = *(const half8*)&xt[w * 16 + mi][ko];
    #pragma unroll
    for (int s = 0; s < 8; ++s){
      half8 a = *(const half8*)&Wt[s * 16 + mi][ko];
      acc[s] = __builtin_amdgcn_mfma_f32_16x16x32_f16(a, b, acc[s], 0, 0, 0);
    }
  }

  int m = m0 + w * 16 + mi;
  float sA = 0.f, dA = 0.f, sB = 0.f, dB = 0.f;
  #pragma unroll
  for (int s = 0; s < 8; ++s){
    int nb = j0 + s * 16 + g * 4;
    float4 asv = *(const float4*)&as1[nb];
    float4 adv = *(const float4*)&ad1[nb];
    float sv = acc[s][0] * asv.x + acc[s][1] * asv.y + acc[s][2] * asv.z + acc[s][3] * asv.w;
    float dv = acc[s][0] * adv.x + acc[s][1] * adv.y + acc[s][2] * adv.z + acc[s][3] * adv.w;
    if (s < 4){ sA += sv; dA += dv; } else { sB += sv; dB += dv; }
    if (m < N_NODES){
      union { __half2 h2[2]; float2 f2; } u;
      u.h2[0] = __floats2half2_rn(acc[s][0], acc[s][1]);
      u.h2[1] = __floats2half2_rn(acc[s][2], acc[s][3]);
      *(float2*)&h1h[(size_t)m * 256 + nb] = u.f2;
    }
  }
  sA += __shfl_xor(sA, 16); sA += __shfl_xor(sA, 32);
  dA += __shfl_xor(dA, 16); dA += __shfl_xor(dA, 32);
  sB += __shfl_xor(sB, 16); sB += __shfl_xor(sB, 32);
  dB += __shfl_xor(dB, 16); dB += __shfl_xor(dB, 32);
  if (g == 0 && m < N_NODES){
    alS[m * 4 + by * 2 + 0] = sA; alD[m * 4 + by * 2 + 0] = dA;
    alS[m * 4 + by * 2 + 1] = sB; alD[m * 4 + by * 2 + 1] = dB;
  }
}

// ---- layer-1 single-pass softmax+aggregate+bias+ELU (unchanged from R12) ----
__global__ __launch_bounds__(256) void k_attn1(
                        const int* __restrict__ cur, const int* __restrict__ adjS,
                        const __half* __restrict__ h1h,
                        const float* __restrict__ alS, const float* __restrict__ alD,
                        const float* __restrict__ b1, _Float16* __restrict__ heluh){
  int b    = blockIdx.x;
  int slot = b & 7;
  int h    = slot & 3;
  int g    = (slot >> 2) * 625 + (b >> 3);    // node group [0,1250)
  int t    = threadIdx.x;
  int w    = t >> 6, lane = t & 63;
  int grp  = lane >> 4, l16 = lane & 15;
  int hf   = l16 >> 3, l8 = l16 & 7;
  int n    = g * 16 + w * 4 + grp;

  int cnt  = cur[n]; cnt = (cnt > MAXDEG) ? MAXDEG : cnt;
  int base = n * MAXDEG;
  float ald = alD[n * 4 + h];
  const __half* __restrict__ hb = h1h + h * 64 + l8 * 8;

  float4 Aa = make_float4(0.f,0.f,0.f,0.f), Ab = Aa;
  float den = 0.f;

  int nq = cnt >> 2;
  for (int q = hf; q < nq; q += 2){
    int4 quad = *(const int4*)&adjS[base + q * 4];   // 16B-aligned
    int s0 = quad.x, s1 = quad.y, s2 = quad.z, s3 = quad.w;
    float t0 = alS[s0 * 4 + h] + ald;
    float t1 = alS[s1 * 4 + h] + ald;
    float t2 = alS[s2 * 4 + h] + ald;
    float t3 = alS[s3 * 4 + h] + ald;
    t0 = (t0 > 0.f) ? t0 : NEG_SLOPE * t0;
    t1 = (t1 > 0.f) ? t1 : NEG_SLOPE * t1;
    t2 = (t2 > 0.f) ? t2 : NEG_SLOPE * t2;
    t3 = (t3 > 0.f) ? t3 : NEG_SLOPE * t3;
    float w0 = __expf(t0), w1 = __expf(t1), w2 = __expf(t2), w3 = __expf(t3);
    float4 r0 = *(const float4*)&hb[(size_t)s0 * 256];
    float4 r1 = *(const float4*)&hb[(size_t)s1 * 256];
    float4 r2 = *(const float4*)&hb[(size_t)s2 * 256];
    float4 r3 = *(const float4*)&hb[(size_t)s3 * 256];
    const __half2* p0 = (const __half2*)&r0;
    const __half2* p1 = (const __half2*)&r1;
    const __half2* p2 = (const __half2*)&r2;
    const __half2* p3 = (const __half2*)&r3;
    {
      float2 a0 = __half22float2(p0[0]), a1 = __half22float2(p0[1]);
      float2 a2 = __half22float2(p0[2]), a3 = __half22float2(p0[3]);
      Aa.x += w0 * a0.x; Aa.y += w0 * a0.y; Aa.z += w0 * a1.x; Aa.w += w0 * a1.y;
      Ab.x += w0 * a2.x; Ab.y += w0 * a2.y; Ab.z += w0 * a3.x; Ab.w += w0 * a3.y;
    }
    {
      float2 a0 = __half22float2(p1[0]), a1 = __half22float2(p1[1]);
      float2 a2 = __half22float2(p1[2]), a3 = __half22float2(p1[3]);
      Aa.x += w1 * a0.x; Aa.y += w1 * a0.y; Aa.z += w1 * a1.x; Aa.w += w1 * a1.y;
      Ab.x += w1 * a2.x; Ab.y += w1 * a2.y; Ab.z += w1 * a3.x; Ab.w += w1 * a3.y;
    }
    {
      float2 a0 = __half22float2(p2[0]), a1 = __half22float2(p2[1]);
      float2 a2 = __half22float2(p2[2]), a3 = __half22float2(p2[3]);
      Aa.x += w2 * a0.x; Aa.y += w2 * a0.y; Aa.z += w2 * a1.x; Aa.w += w2 * a1.y;
      Ab.x += w2 * a2.x; Ab.y += w2 * a2.y; Ab.z += w2 * a3.x; Ab.w += w2 * a3.y;
    }
    {
      float2 a0 = __half22float2(p3[0]), a1 = __half22float2(p3[1]);
      float2 a2 = __half22float2(p3[2]), a3 = __half22float2(p3[3]);
      Aa.x += w3 * a0.x; Aa.y += w3 * a0.y; Aa.z += w3 * a1.x; Aa.w += w3 * a1.y;
      Ab.x += w3 * a2.x; Ab.y += w3 * a2.y; Ab.z += w3 * a3.x; Ab.w += w3 * a3.y;
    }
    den += ((w0 + w1) + (w2 + w3));
  }
  if ((nq & 1) == hf){
    for (int i = base + nq * 4; i < base + cnt; ++i){
      int s0 = adjS[i];
      float t0 = alS[s0 * 4 + h] + ald;
      t0 = (t0 > 0.f) ? t0 : NEG_SLOPE * t0;
      float w0 = __expf(t0);
      float4 r0 = *(const float4*)&hb[(size_t)s0 * 256];
      const __half2* p0 = (const __half2*)&r0;
      float2 a0 = __half22float2(p0[0]), a1 = __half22float2(p0[1]);
      float2 a2 = __half22float2(p0[2]), a3 = __half22float2(p0[3]);
      Aa.x += w0 * a0.x; Aa.y += w0 * a0.y; Aa.z += w0 * a1.x; Aa.w += w0 * a1.y;
      Ab.x += w0 * a2.x; Ab.y += w0 * a2.y; Ab.z += w0 * a3.x; Ab.w += w0 * a3.y;
      den += w0;
    }
  }
  Aa.x += __shfl_xor(Aa.x, 8); Aa.y += __shfl_xor(Aa.y, 8);
  Aa.z += __shfl_xor(Aa.z, 8); Aa.w += __shfl_xor(Aa.w, 8);
  Ab.x += __shfl_xor(Ab.x, 8); Ab.y += __shfl_xor(Ab.y, 8);
  Ab.z += __shfl_xor(Ab.z, 8); Ab.w += __shfl_xor(Ab.w, 8);
  den  += __shfl_xor(den, 8);

  if (hf == 0){
    float rinv = 1.f / (den + 1e-16f);
    float4 bv0 = *(const float4*)&b1[h * 64 + l8 * 8];
    float4 bv1 = *(const float4*)&b1[h * 64 + l8 * 8 + 4];
    float o0 = Aa.x * rinv + bv0.x;
    float o1 = Aa.y * rinv + bv0.y;
    float o2 = Aa.z * rinv + bv0.z;
    float o3 = Aa.w * rinv + bv0.w;
    float o4 = Ab.x * rinv + bv1.x;
    float o5 = Ab.y * rinv + bv1.y;
    float o6 = Ab.z * rinv + bv1.z;
    float o7 = Ab.w * rinv + bv1.w;
    o0 = (o0 > 0.f) ? o0 : (__expf(o0) - 1.f);
    o1 = (o1 > 0.f) ? o1 : (__expf(o1) - 1.f);
    o2 = (o2 > 0.f) ? o2 : (__expf(o2) - 1.f);
    o3 = (o3 > 0.f) ? o3 : (__expf(o3) - 1.f);
    o4 = (o4 > 0.f) ? o4 : (__expf(o4) - 1.f);
    o5 = (o5 > 0.f) ? o5 : (__expf(o5) - 1.f);
    o6 = (o6 > 0.f) ? o6 : (__expf(o6) - 1.f);
    o7 = (o7 > 0.f) ? o7 : (__expf(o7) - 1.f);
    union { __half2 h2[4]; half8 h8; } u;
    u.h2[0] = __floats2half2_rn(o0, o1);
    u.h2[1] = __floats2half2_rn(o2, o3);
    u.h2[2] = __floats2half2_rn(o4, o5);
    u.h2[3] = __floats2half2_rn(o6, o7);
    *(half8*)&heluh[(size_t)n * 256 + h * 64 + l8 * 8] = u.h8;
  }
}

// ---- GEMM2 via MFMA fp16 (unchanged) ----
__global__ __launch_bounds__(256) void k_gemm2(
                        const _Float16* __restrict__ heluh, const float* __restrict__ W2,
                        const float* __restrict__ as2, const float* __restrict__ ad2,
                        float* __restrict__ h2, float* __restrict__ alS, float* __restrict__ alD){
  __shared__ _Float16 Ht[64][264];   // [node][k], pad 8
  __shared__ _Float16 Wt[16][264];   // [col][k]
  int t = threadIdx.x;
  int n0 = blockIdx.x * 64;
  #pragma unroll
  for (int ii = 0; ii < 8; ++ii){
    int f = t + ii * 256;            // 2048 slots = 64 rows x 32 half8
    int r = f >> 5, s = f & 31;
    half8 v = (half8)(_Float16)0.f;
    if (n0 + r < N_NODES) v = *(const half8*)&heluh[(size_t)(n0 + r) * 256 + s * 8];
    *(half8*)&Ht[r][s * 8] = v;
  }
  {                                   // W2 [256 k][16 col] fp32 -> Wt[16][256] fp16
    int k = t;
    float4 w0 = *(const float4*)&W2[k * 16 + 0];
    float4 w1 = *(const float4*)&W2[k * 16 + 4];
    float4 w2 = *(const float4*)&W2[k * 16 + 8];
    float4 w3 = *(const float4*)&W2[k * 16 + 12];
    float wv[16] = {w0.x,w0.y,w0.z,w0.w, w1.x,w1.y,w1.z,w1.w,
                    w2.x,w2.y,w2.z,w2.w, w3.x,w3.y,w3.z,w3.w};
    #pragma unroll
    for (int c = 0; c < 16; ++c) Wt[c][k] = (_Float16)wv[c];
  }
  __syncthreads();

  int w = t >> 6, lane = t & 63;
  int g = lane >> 4, mi = lane & 15;
  f32x4 acc = {};
  #pragma unroll
  for (int kk = 0; kk < 8; ++kk){
    int ko = kk * 32 + g * 8;
    half8 b = *(const half8*)&Ht[w * 16 + mi][ko];
    half8 a = *(const half8*)&Wt[mi][ko];
    acc = __builtin_amdgcn_mfma_f32_16x16x32_f16(a, b, acc, 0, 0, 0);
  }
  int n = n0 + w * 16 + mi;
  float4 asv = *(const float4*)&as2[g * 4];
  float4 adv = *(const float4*)&ad2[g * 4];
  float s_ = acc[0] * asv.x + acc[1] * asv.y + acc[2] * asv.z + acc[3] * asv.w;
  float d_ = acc[0] * adv.x + acc[1] * adv.y + acc[2] * adv.z + acc[3] * adv.w;
  s_ += __shfl_xor(s_, 16); s_ += __shfl_xor(s_, 32);
  d_ += __shfl_xor(d_, 16); d_ += __shfl_xor(d_, 32);
  if (n < N_NODES){
    float4 hv = make_float4(acc[0], acc[1], acc[2], acc[3]);
    *(float4*)&h2[(size_t)n * 16 + g * 4] = hv;   // pre-bias
    if (g == 0){ alS[n] = s_; alD[n] = d_; }
  }
}

// ---- layer-2 single-pass softmax+aggregate+bias -> d_out (unchanged) ----
__global__ __launch_bounds__(256) void k_attn2(
                        const int* __restrict__ cur, const int* __restrict__ adjS,
                        const float* __restrict__ h2,
                        const float* __restrict__ alS, const float* __restrict__ alD,
                        const float* __restrict__ b2, float* __restrict__ out){
  int t    = threadIdx.x;
  int w    = t >> 6, lane = t & 63;
  int grp  = lane >> 4, l16 = lane & 15;
  int j    = l16 >> 2, c4 = l16 & 3;
  int n    = blockIdx.x * 16 + w * 4 + grp;

  int cnt  = cur[n]; cnt = (cnt > MAXDEG) ? MAXDEG : cnt;
  int start = n * MAXDEG, end = start + cnt;
  float ald = alD[n];
  float4 acc = make_float4(0.f,0.f,0.f,0.f);
  float den = 0.f;
  for (int i = start + j; i < end; i += 4){
    int s = adjS[i];
    float tt = alS[s] + ald;
    tt = (tt > 0.f) ? tt : NEG_SLOPE * tt;
    float wv = __expf(tt);
    float4 v = *(const float4*)&h2[(size_t)s * 16 + c4 * 4];
    acc.x += wv * v.x; acc.y += wv * v.y; acc.z += wv * v.z; acc.w += wv * v.w;
    den += wv;
  }
  #pragma unroll
  for (int off = 4; off <= 8; off <<= 1){
    acc.x += __shfl_xor(acc.x, off);
    acc.y += __shfl_xor(acc.y, off);
    acc.z += __shfl_xor(acc.z, off);
    acc.w += __shfl_xor(acc.w, off);
    den   += __shfl_xor(den, off);
  }
  if (j == 0){
    float rinv = 1.f / (den + 1e-16f);
    float4 bv = *(const float4*)&b2[c4 * 4];
    float4 o;
    o.x = acc.x * rinv + bv.x; o.y = acc.y * rinv + bv.y;
    o.z = acc.z * rinv + bv.z; o.w = acc.w * rinv + bv.w;
    *(float4*)&out[(size_t)n * 16 + c4 * 4] = o;
  }
}

extern "C" void kernel_launch(void* const* d_in, const int* in_sizes, int n_in,
                              void* d_out, int out_size, void* d_ws, size_t ws_size,
                              hipStream_t stream){
  const float* x   = (const float*)d_in[0];
  const int*   ei  = (const int*)d_in[1];
  const float* W1  = (const float*)d_in[2];
  const float* as1 = (const float*)d_in[3];
  const float* ad1 = (const float*)d_in[4];
  const float* b1  = (const float*)d_in[5];
  const float* W2  = (const float*)d_in[6];
  const float* as2 = (const float*)d_in[7];
  const float* ad2 = (const float*)d_in[8];
  const float* b2  = (const float*)d_in[9];
  float* out = (float*)d_out;

  float* fws = (float*)d_ws;
  size_t off = 0;
  __half* h1h = (__half*)(fws + off); off += (size_t)N_NODES * 128;      // fp16 [20000,256]
  _Float16* W1t = (_Float16*)(fws + off); off += 256 * 64;                // fp16 [256,128]
  _Float16* heluh = (_Float16*)(fws + off); off += (size_t)N_NODES * 128; // fp16 [20000,256]
  float* h2   = fws + off; off += (size_t)N_NODES * 16;
  float* alS1 = fws + off; off += N_NODES * 4;
  float* alD1 = fws + off; off += N_NODES * 4;
  float* alS2 = fws + off; off += N_NODES;
  float* alD2 = fws + off; off += N_NODES;
  int* cur  = (int*)(fws + off); off += N_NODES;
  int* adjS = (int*)(fws + off); off += (size_t)N_NODES * MAXDEG;

  k_init<<<(N_NODES + 255) / 256, 256, 0, stream>>>(cur, W1, W1t);
  k_gemm1<<<dim3(313, 2), 256, 0, stream>>>(x, W1t, as1, ad1, (_Float16*)h1h,
                                            alS1, alD1, ei, cur, adjS);
  k_attn1<<<5000, 256, 0, stream>>>(cur, adjS, h1h, alS1, alD1, b1, heluh);
  k_gemm2<<<313, 256, 0, stream>>>(heluh, W2, as2, ad2, h2, alS2, alD2);
  k_attn2<<<1250, 256, 0, stream>>>(cur, adjS, h2, alS2, alD2, b2, out);
}